// Round 14
// baseline (1030.863 us; speedup 1.0000x reference)
//
#include <hip/hip_runtime.h>
#include <hip/hip_bf16.h>
#include <math.h>

using bf16 = __hip_bfloat16;
typedef float f32x4 __attribute__((ext_vector_type(4)));
typedef short short8 __attribute__((ext_vector_type(8)));

constexpr int kD = 512, kH = 8, kDk = 64, kF = 2048, kV = 32000;
constexpr int kB = 2, kS = 1024, kM = 2048, kBH = 16;  // kM = B*S tokens

enum { ST_F32 = 0, ST_BF16, ST_QKV };

__device__ __forceinline__ void gload_lds16(const void* g, void* l) {
  __builtin_amdgcn_global_load_lds(
      (const __attribute__((address_space(1))) void*)g,
      (__attribute__((address_space(3))) void*)l, 16, 0, 0);
}

__device__ __forceinline__ float bfu2f(short u) {
  union { unsigned int i; float f; } c;
  c.i = ((unsigned int)(unsigned short)u) << 16;
  return c.f;
}

// LayerNorm (unbiased /511, eps 1e-6) of rows vb*4..vb*4+3 (wave per row), fp32 -> bf16
__device__ __forceinline__ void ln4(int vb, const float* __restrict__ x,
                                    const float* __restrict__ g,
                                    const float* __restrict__ b,
                                    bf16* __restrict__ out) {
  int w = threadIdx.x >> 6, lane = threadIdx.x & 63;
  int row = vb * 4 + w;
  const float* xp = x + (size_t)row * kD;
  float v[8];
  float sum = 0.f;
#pragma unroll
  for (int i = 0; i < 8; ++i) { v[i] = xp[lane + i * 64]; sum += v[i]; }
#pragma unroll
  for (int o = 32; o; o >>= 1) sum += __shfl_xor(sum, o);
  float mean = sum * (1.f / 512.f);
  float sq = 0.f;
#pragma unroll
  for (int i = 0; i < 8; ++i) { float d = v[i] - mean; sq += d * d; }
#pragma unroll
  for (int o = 32; o; o >>= 1) sq += __shfl_xor(sq, o);
  float inv = rsqrtf(sq * (1.f / 511.f) + 1e-6f);
  bf16* op = out + (size_t)row * kD;
#pragma unroll
  for (int i = 0; i < 8; ++i) {
    int d = lane + i * 64;
    op[d] = __float2bfloat16(g[d] * (v[i] - mean) * inv + b[d]);
  }
}

// ---------------- generic MFMA GEMM: C = A[M,K] @ Bt[N,K]^T (+bias)(+relu)(+res)
// 64x64 tiles, 4 waves, 3-deep counted-vmcnt pipeline, XOR-swizzled LDS (R13).
// FUSELN (R14): after epilogue stores, blocks arrive at cnt[blockIdx.y] with an
// ACQ_REL device-scope RMW (R12-validated release/acquire pattern); the LAST of the
// gridDim.x column-blocks re-reads its 64-row panel of Cv (fp32) and LayerNorms it
// into lnout. Kills the separate k_ln launch per site.
template <int BM, int BN, int STM, bool BIAS, bool RELU, bool RES, int NBUF, bool XSWZ,
          bool ASEL, bool FUSELN>
__launch_bounds__(256)
__global__ void k_gemm(const bf16* __restrict__ A, int lda, long long Az,
                       const bf16* __restrict__ Bt, int ldb, long long Bz,
                       void* __restrict__ Cv, int ldc, long long Cz,
                       int K, float alpha,
                       const float* __restrict__ bias,
                       const float* __restrict__ res,
                       const bf16* __restrict__ A2,
                       const float* __restrict__ lng,
                       const float* __restrict__ lnb,
                       bf16* __restrict__ lnout,
                       unsigned* __restrict__ cnt) {
  static_assert(NBUF == 1 || (BM == 64 && BN == 64), "pipeline path sized for 64x64");
  constexpr int FM = BM / 32, FN = BN / 32;
  __shared__ __attribute__((aligned(16))) bf16 As[NBUF][BM * 64];
  __shared__ __attribute__((aligned(16))) bf16 Bs[NBUF][BN * 64];
  const int tid = threadIdx.x;
  const int w = tid >> 6, lane = tid & 63;
  int bx = blockIdx.x, by = blockIdx.y;
  if constexpr (XSWZ) {
    const int nx = gridDim.x, ny = gridDim.y;
    const int lin = by * nx + bx;
    const int cpx = (nx * ny) >> 3;
    const int s = (lin & 7) * cpx + (lin >> 3);
    bx = s / ny;
    by = s - bx * ny;
  }
  const int bm = by * BM, bn = bx * BN;
  const int z = blockIdx.z;
  if constexpr (ASEL) { if (bn >= 512) A = A2; }
  A += (long long)z * Az;
  Bt += (long long)z * Bz;
  const int l15 = lane & 15, lhi = lane >> 4;
  const int wr = (w >> 1) * (BM / 2), wc = (w & 1) * (BN / 2);
  f32x4 acc[FM][FN] = {};
  const int nkt = K >> 6;  // BK = 64

  auto stage = [&](int kt, int nb) {
#pragma unroll
    for (int it = 0; it < BM / 32; ++it) {
      int chunk = (it * 4 + w) * 64 + lane;        // 16B chunks, LDS-linear dest
      int row = chunk >> 3, c = chunk & 7;
      int col = (c ^ (row & 7)) << 3;              // pre-swizzled global source
      gload_lds16(A + (size_t)(bm + row) * lda + kt * 64 + col, As[nb] + (it * 4 + w) * 512);
    }
#pragma unroll
    for (int it = 0; it < BN / 32; ++it) {
      int chunk = (it * 4 + w) * 64 + lane;
      int row = chunk >> 3, c = chunk & 7;
      int col = (c ^ (row & 7)) << 3;
      gload_lds16(Bt + (size_t)(bn + row) * ldb + kt * 64 + col, Bs[nb] + (it * 4 + w) * 512);
    }
  };
  auto compute = [&](int cb) {
#pragma unroll
    for (int kk = 0; kk < 2; ++kk) {
      short8 af[FM], bf[FN];
#pragma unroll
      for (int i = 0; i < FM; ++i) {
        int row = wr + i * 16 + l15;
        af[i] = *(const short8*)(As[cb] + row * 64 + (((kk * 4 + lhi) ^ (row & 7)) * 8));
      }
#pragma unroll
      for (int j = 0; j < FN; ++j) {
        int row = wc + j * 16 + l15;
        bf[j] = *(const short8*)(Bs[cb] + row * 64 + (((kk * 4 + lhi) ^ (row & 7)) * 8));
      }
#pragma unroll
      for (int i = 0; i < FM; ++i)
#pragma unroll
        for (int j = 0; j < FN; ++j)
          acc[i][j] = __builtin_amdgcn_mfma_f32_16x16x32_bf16(af[i], bf[j], acc[i][j], 0, 0, 0);
    }
  };

  if constexpr (NBUF == 3) {
    stage(0, 0);
    stage(1, 1);
    stage(2, 2);                                   // 12 loads out
    asm volatile("s_waitcnt vmcnt(8)" ::: "memory");  // tile0 landed
    __builtin_amdgcn_s_barrier();
    __builtin_amdgcn_sched_barrier(0);
    int cur = 0;
    for (int kt = 0; kt < nkt; ++kt) {
      compute(cur);
      asm volatile("s_waitcnt lgkmcnt(0)" ::: "memory");  // ds_reads of buf[cur] done
      __builtin_amdgcn_sched_barrier(0);
      if (kt + 1 < nkt) {
        __builtin_amdgcn_s_barrier();        // all waves done reading buf[cur]
        if (kt + 3 < nkt) {
          stage(kt + 3, cur);                // overwrite buf[cur]; 12 out
          asm volatile("s_waitcnt vmcnt(8)" ::: "memory");  // stage(kt+1) landed
        } else {
          asm volatile("s_waitcnt vmcnt(0)" ::: "memory");
        }
        __builtin_amdgcn_s_barrier();        // all waves confirm next buf ready
        __builtin_amdgcn_sched_barrier(0);
      }
      cur = (cur == 2) ? 0 : cur + 1;
    }
  } else {
    for (int kt = 0; kt < nkt; ++kt) {
      stage(kt, 0);
      __syncthreads();
      compute(0);
      __syncthreads();
    }
  }

  // epilogue: C/D layout col=lane&15, row=(lane>>4)*4+r (m89-verified)
#pragma unroll
  for (int i = 0; i < FM; ++i) {
#pragma unroll
    for (int j = 0; j < FN; ++j) {
#pragma unroll
      for (int r = 0; r < 4; ++r) {
        int m = bm + wr + i * 16 + lhi * 4 + r;
        int n = bn + wc + j * 16 + l15;
        float val = acc[i][j][r] * alpha;
        if constexpr (BIAS) val += bias[n];
        if constexpr (RELU) val = fmaxf(val, 0.f);
        if constexpr (RES) val += res[(size_t)m * ldc + n];
        if constexpr (STM == ST_F32) {
          ((float*)Cv)[(size_t)z * Cz + (size_t)m * ldc + n] = val;
        } else if constexpr (STM == ST_BF16) {
          ((bf16*)Cv)[(size_t)z * Cz + (size_t)m * ldc + n] = __float2bfloat16(val);
        } else if constexpr (STM == ST_QKV) {    // n<512->Q, <1024->K (both [B,H,S,dk]), else V^T [B,H,dk,S]
          int seg = n >> 9, nn = n & 511;
          int b_ = m >> 10, s_ = m & 1023, h_ = nn >> 6, d_ = nn & 63;
          size_t idx = (seg < 2)
              ? (((size_t)(b_ * kH + h_) << 10) + s_) * kDk + d_
              : ((size_t)(b_ * kH + h_) * kDk + d_) * kS + s_;
          ((bf16*)Cv)[(size_t)seg * 1048576 + idx] = __float2bfloat16(val);
        }
      }
    }
  }

  if constexpr (FUSELN) {
    // stores drained at barrier; release via ACQ_REL RMW; last arriver acquires and
    // re-reads the full 64-row panel (its own 64 cols + 7 peers') for LN.
    __threadfence();
    __syncthreads();
    __shared__ int lastf;
    if (tid == 0) {
      unsigned v = __hip_atomic_fetch_add(&cnt[blockIdx.y], 1u,
                                          __ATOMIC_ACQ_REL, __HIP_MEMORY_SCOPE_AGENT);
      lastf = (v == gridDim.x - 1u) ? 1 : 0;
    }
    __syncthreads();
    if (lastf) {
      const float* xsrc = (const float*)Cv;    // ST_F32 xio, ldc == kD at all FUSELN sites
#pragma unroll
      for (int i = 0; i < BM / 4; ++i) ln4((bm >> 2) + i, xsrc, lng, lnb, lnout);
    }
  }
}

// ---------------- fused flash attention (unchanged from R13)
template <bool CAUSAL>
__launch_bounds__(256)
__global__ void k_fattn(const bf16* __restrict__ Q, const bf16* __restrict__ K,
                        const bf16* __restrict__ Vt, bf16* __restrict__ O) {
  __shared__ __attribute__((aligned(16))) bf16 Ks[3][4096];
  __shared__ __attribute__((aligned(16))) bf16 Vs[3][4096];
  __shared__ __attribute__((aligned(16))) bf16 Ps[4][1024];
  const int tid = threadIdx.x, w = tid >> 6, lane = tid & 63;
  const int l15 = lane & 15, lhi = lane >> 4;
  const int q0 = blockIdx.x * 64, bh = blockIdx.y;
  const int qw = q0 + w * 16;
  const bf16* Qp = Q + (((size_t)(bh << 10)) + qw + l15) * kDk;
  short8 aq[2];
  aq[0] = *(const short8*)(Qp + lhi * 8);
  aq[1] = *(const short8*)(Qp + 32 + lhi * 8);
  const int srow = w * 8 + (lane >> 3);
  const int sc = (lane & 7) ^ (srow & 7);
  const bf16* Ksrc = K + (((size_t)(bh << 10)) + srow) * kDk + sc * 8;
  const bf16* Vsrc = Vt + ((size_t)bh * kDk + srow) * kS + sc * 8;
  const int nt = CAUSAL ? (q0 >> 6) + 1 : (kS >> 6);

  auto stage = [&](int t, int nb) {
    int kv0 = t << 6;
    gload_lds16(Ksrc + (size_t)kv0 * kDk, Ks[nb] + w * 512);
    gload_lds16(Ksrc + (size_t)(kv0 + 32) * kDk, Ks[nb] + 2048 + w * 512);
    gload_lds16(Vsrc + kv0, Vs[nb] + w * 512);
    gload_lds16(Vsrc + kv0 + 32 * kS, Vs[nb] + 2048 + w * 512);
  };

  float m_[4], l_[4];
#pragma unroll
  for (int r = 0; r < 4; ++r) { m_[r] = -1e30f; l_[r] = 0.f; }
  f32x4 ao[4] = {};

  stage(0, 0);
  if (nt > 2) {
    stage(1, 1);
    stage(2, 2);
    asm volatile("s_waitcnt vmcnt(8)" ::: "memory");
  } else if (nt > 1) {
    stage(1, 1);
    asm volatile("s_waitcnt vmcnt(4)" ::: "memory");
  } else {
    asm volatile("s_waitcnt vmcnt(0)" ::: "memory");
  }
  __builtin_amdgcn_s_barrier();
  __builtin_amdgcn_sched_barrier(0);

  int cur = 0;
  for (int t = 0; t < nt; ++t) {
    f32x4 as[4] = {};
#pragma unroll
    for (int kk = 0; kk < 2; ++kk) {
      short8 bk[4];
#pragma unroll
      for (int nf = 0; nf < 4; ++nf) {
        int row = nf * 16 + l15;
        int c = (4 * kk + lhi) ^ (row & 7);
        bk[nf] = *(const short8*)(Ks[cur] + row * 64 + c * 8);
      }
#pragma unroll
      for (int nf = 0; nf < 4; ++nf)
        as[nf] = __builtin_amdgcn_mfma_f32_16x16x32_bf16(aq[kk], bk[nf], as[nf], 0, 0, 0);
    }
    float s[4][4];
#pragma unroll
    for (int nf = 0; nf < 4; ++nf)
#pragma unroll
      for (int r = 0; r < 4; ++r) {
        float v = as[nf][r] * 0.125f;
        if (CAUSAL && t == nt - 1) {
          int col = (t << 6) + nf * 16 + l15;
          int row = qw + lhi * 4 + r;
          if (col > row) v = -1e30f;
        }
        s[nf][r] = v;
      }
    float mn[4], scl[4], rsum[4];
#pragma unroll
    for (int r = 0; r < 4; ++r) {
      float mx = fmaxf(fmaxf(s[0][r], s[1][r]), fmaxf(s[2][r], s[3][r]));
      mx = fmaxf(mx, __shfl_xor(mx, 1));
      mx = fmaxf(mx, __shfl_xor(mx, 2));
      mx = fmaxf(mx, __shfl_xor(mx, 4));
      mx = fmaxf(mx, __shfl_xor(mx, 8));
      mn[r] = fmaxf(m_[r], mx);
      scl[r] = __expf(m_[r] - mn[r]);
      rsum[r] = 0.f;
    }
#pragma unroll
    for (int nf = 0; nf < 4; ++nf)
#pragma unroll
      for (int r = 0; r < 4; ++r) {
        float p = __expf(s[nf][r] - mn[r]);
        rsum[r] += p;
        int pr = lhi * 4 + r;
        int c = (2 * nf + (l15 >> 3)) ^ (pr & 7);
        Ps[w][pr * 64 + c * 8 + (l15 & 7)] = __float2bfloat16(p);
      }
#pragma unroll
    for (int r = 0; r < 4; ++r) {
      float su = rsum[r];
      su += __shfl_xor(su, 1);
      su += __shfl_xor(su, 2);
      su += __shfl_xor(su, 4);
      su += __shfl_xor(su, 8);
      l_[r] = l_[r] * scl[r] + su;
      m_[r] = mn[r];
    }
#pragma unroll
    for (int nf = 0; nf < 4; ++nf)
#pragma unroll
      for (int r = 0; r < 4; ++r) ao[nf][r] *= scl[r];
    asm volatile("s_waitcnt lgkmcnt(0)" ::: "memory");
    __builtin_amdgcn_sched_barrier(0);
#pragma unroll
    for (int kk = 0; kk < 2; ++kk) {
      short8 pa = *(const short8*)(Ps[w] + l15 * 64 + (((4 * kk + lhi) ^ (l15 & 7)) * 8));
      short8 bv[4];
#pragma unroll
      for (int nf = 0; nf < 4; ++nf) {
        int row = nf * 16 + l15;
        int c = (4 * kk + lhi) ^ (row & 7);
        bv[nf] = *(const short8*)(Vs[cur] + row * 64 + c * 8);
      }
#pragma unroll
      for (int nf = 0; nf < 4; ++nf)
        ao[nf] = __builtin_amdgcn_mfma_f32_16x16x32_bf16(pa, bv[nf], ao[nf], 0, 0, 0);
    }
    asm volatile("s_waitcnt lgkmcnt(0)" ::: "memory");
    __builtin_amdgcn_sched_barrier(0);
    if (t + 1 < nt) {
      __builtin_amdgcn_s_barrier();
      if (t + 3 < nt) {
        stage(t + 3, cur);
        asm volatile("s_waitcnt vmcnt(8)" ::: "memory");
      } else {
        asm volatile("s_waitcnt vmcnt(0)" ::: "memory");
      }
      __builtin_amdgcn_s_barrier();
      __builtin_amdgcn_sched_barrier(0);
    }
    cur = (cur == 2) ? 0 : cur + 1;
  }
  const int b_ = bh >> 3, h_ = bh & 7;
  float inv[4];
#pragma unroll
  for (int r = 0; r < 4; ++r) inv[r] = 1.f / l_[r];
#pragma unroll
  for (int nf = 0; nf < 4; ++nf)
#pragma unroll
    for (int r = 0; r < 4; ++r) {
      int q = qw + lhi * 4 + r;
      O[((size_t)(b_ * kS + q)) * kD + h_ * kDk + nf * 16 + l15] =
          __float2bfloat16(ao[nf][r] * inv[r]);
    }
}

// ---------------- prep: weight transposes + embed(+inline LN of each full row), 1 launch
struct TJobs {
  const float* src[8];
  bf16* dst[8];
  int K[8], N[8];
  int ofs[9];
};

struct PrepArgs {
  TJobs tj; int ntile;
  const int *src, *tgt;
  const float *src_emb, *tgt_emb;
  const float *eg, *eb, *dg, *db;   // first-LN params (enc l0, dec l0)
  float *x_enc, *x_dec;
  bf16 *hb_enc, *hb_dec;
};

__global__ void k_prep(PrepArgs P) {
  __shared__ float t[32][33];
  __shared__ float red[4], red2[4];
  const int tid = threadIdx.x;
  if ((int)blockIdx.x < P.ntile) {
    const int tb = blockIdx.x;
    int j = 0;
#pragma unroll
    for (int i = 1; i < 8; ++i) j += (tb >= P.tj.ofs[i]) ? 1 : 0;
    const int K = P.tj.K[j], N = P.tj.N[j];
    const int tn = N >> 5, tk = K >> 5;
    int r = tb - P.tj.ofs[j];
    const int z = r / (tn * tk);
    r -= z * tn * tk;
    const int k0 = (r / tn) << 5, n0 = (r % tn) << 5;
    const float* Wp = P.tj.src[j] + (size_t)z * K * N;
    bf16* WTp = P.tj.dst[j] + (size_t)z * K * N;
    const int tx = tid & 31, ty = tid >> 5;
#pragma unroll
    for (int rr = 0; rr < 32; rr += 8)
      t[ty + rr][tx] = Wp[(size_t)(k0 + ty + rr) * N + n0 + tx];
    __syncthreads();
#pragma unroll
    for (int rr = 0; rr < 32; rr += 8)
      WTp[(size_t)(n0 + ty + rr) * K + k0 + tx] = __float2bfloat16(t[tx][ty + rr]);
    return;
  }
  // embed + inline LN: block owns one full token row
  const int vb = blockIdx.x - P.ntile;
  const int m = vb & (kM - 1), which = vb >> 11;
  const int* tok = which ? P.tgt : P.src;
  const float* emb = which ? P.tgt_emb : P.src_emb;
  float* x = which ? P.x_dec : P.x_enc;
  const int s = m & (kS - 1);
  const float* e = emb + (size_t)tok[m] * kD;
  float* xp = x + (size_t)m * kD;
  float v[2];
#pragma unroll
  for (int h = 0; h < 2; ++h) {
    int d = tid + h * 256;
    int i = d >> 1;
    float freq = __expf(-(float)(2 * i) * (9.210340371976184f / 512.0f));
    float ang = (float)s * freq;
    float pe = (d & 1) ? cosf(ang) : sinf(ang);
    v[h] = e[d] * 22.62741699796952f + pe;
    xp[d] = v[h];
  }
  const int w = tid >> 6, lane = tid & 63;
  float sum = v[0] + v[1];
#pragma unroll
  for (int o = 32; o; o >>= 1) sum += __shfl_xor(sum, o);
  if (lane == 0) red[w] = sum;
  __syncthreads();
  sum = red[0] + red[1] + red[2] + red[3];
  const float mean = sum * (1.f / 512.f);
  float sq = (v[0] - mean) * (v[0] - mean) + (v[1] - mean) * (v[1] - mean);
#pragma unroll
  for (int o = 32; o; o >>= 1) sq += __shfl_xor(sq, o);
  if (lane == 0) red2[w] = sq;
  __syncthreads();
  sq = red2[0] + red2[1] + red2[2] + red2[3];
  const float rstd = rsqrtf(sq * (1.f / 511.f) + 1e-6f);
  const float* g = which ? P.dg : P.eg;
  const float* b = which ? P.db : P.eb;
  bf16* hb = (which ? P.hb_dec : P.hb_enc) + (size_t)m * kD;
#pragma unroll
  for (int h = 0; h < 2; ++h) {
    int d = tid + h * 256;
    hb[d] = __float2bfloat16(g[d] * (v[h] - mean) * rstd + b[d]);
  }
}

// ---------------- 256^2-tile proj GEMM (unchanged)
__global__ __launch_bounds__(512, 1) void k_proj256(const bf16* __restrict__ A,
                                                    const bf16* __restrict__ Bt,
                                                    bf16* __restrict__ C,
                                                    const float* __restrict__ bias) {
  __shared__ __attribute__((aligned(16))) bf16 As[4][256 * 32];
  __shared__ __attribute__((aligned(16))) bf16 Bs[4][256 * 32];
  const int tid = threadIdx.x, w = tid >> 6, lane = tid & 63;
  const int l15 = lane & 15, lhi = lane >> 4;
  const int lin = blockIdx.y * 125 + blockIdx.x;
  const int s = (lin & 7) * 125 + (lin >> 3);
  const int bx = s >> 3, by = s & 7;
  const int bm = by * 256, bn = bx * 256;
  const int wr = (w >> 2) * 128, wc = (w & 3) * 64;
  const int rowq = tid >> 2, chk = tid & 3;
  const int swz = (chk ^ ((rowq >> 1) & 3)) << 3;
  const bf16* Asrc0 = A + (size_t)(bm + rowq) * kD + swz;
  const bf16* Asrc1 = A + (size_t)(bm + 128 + rowq) * kD + swz;
  const bf16* Bsrc0 = Bt + (size_t)(bn + rowq) * kD + swz;
  const bf16* Bsrc1 = Bt + (size_t)(bn + 128 + rowq) * kD + swz;
  const int ldsoff = w * 1024;

  auto stage = [&](int kt) {
    const int b = kt & 3;
    const int ko = kt * 32;
    gload_lds16(Asrc0 + ko, (char*)As[b] + ldsoff);
    gload_lds16(Asrc1 + ko, (char*)As[b] + 8192 + ldsoff);
    gload_lds16(Bsrc0 + ko, (char*)Bs[b] + ldsoff);
    gload_lds16(Bsrc1 + ko, (char*)Bs[b] + 8192 + ldsoff);
  };

  const int ra = wr + l15, rb = wc + l15;
  const int abase = ra * 64 + ((lhi ^ ((ra >> 1) & 3)) << 4);
  const int bbase = rb * 64 + ((lhi ^ ((rb >> 1) & 3)) << 4);

  f32x4 acc[8][4] = {};
  stage(0); stage(1); stage(2);
  for (int kt = 0; kt < 16; ++kt) {
    if (kt + 2 < 16)      asm volatile("s_waitcnt vmcnt(8)" ::: "memory");
    else if (kt + 1 < 16) asm volatile("s_waitcnt vmcnt(4)" ::: "memory");
    else                  asm volatile("s_waitcnt vmcnt(0)" ::: "memory");
    __builtin_amdgcn_s_barrier();
    __builtin_amdgcn_sched_barrier(0);
    if (kt + 3 < 16) stage(kt + 3);
    const int b = kt & 3;
    short8 af[8], bf[4];
#pragma unroll
    for (int i = 0; i < 8; ++i)
      af[i] = *(const short8*)((const char*)As[b] + abase + i * 1024);
#pragma unroll
    for (int j = 0; j < 4; ++j)
      bf[j] = *(const short8*)((const char*)Bs[b] + bbase + j * 1024);
#pragma unroll
    for (int i = 0; i < 8; ++i)
#pragma unroll
      for (int j = 0; j < 4; ++j)
        acc[i][j] = __builtin_amdgcn_mfma_f32_16x16x32_bf16(af[i], bf[j], acc[i][j], 0, 0, 0);
    asm volatile("s_waitcnt lgkmcnt(0)" ::: "memory");
    __builtin_amdgcn_sched_barrier(0);
  }
#pragma unroll
  for (int i = 0; i < 8; ++i)
#pragma unroll
    for (int j = 0; j < 4; ++j)
#pragma unroll
      for (int r = 0; r < 4; ++r) {
        int m = bm + wr + i * 16 + lhi * 4 + r;
        int n = bn + wc + j * 16 + l15;
        C[(size_t)m * kV + n] = __float2bfloat16(acc[i][j][r] + bias[n]);
      }
}

// ---------------- log_softmax: bf16 logits -> fp32 out (unchanged)
__global__ __launch_bounds__(640, 2) void k_lsm_bf(const bf16* __restrict__ L,
                                                   float* __restrict__ y) {
  const bf16* row = L + (size_t)blockIdx.x * kV;
  float* orow = y + (size_t)blockIdx.x * kV;
  const int t = threadIdx.x;
  const bool extra = t < 160;
  float v[56];
  float sum = 0.f;
#pragma unroll
  for (int i = 0; i < 6; ++i) {
    short8 s = *(const short8*)(row + (t + i * 640) * 8);
#pragma unroll
    for (int e = 0; e < 8; ++e) {
      float f = bfu2f(s[e]);
      v[i * 8 + e] = f;
      sum += __expf(f);
    }
  }
  if (extra) {
    short8 s = *(const short8*)(row + (3840 + t) * 8);
#pragma unroll
    for (int e = 0; e < 8; ++e) {
      float f = bfu2f(s[e]);
      v[48 + e] = f;
      sum += __expf(f);
    }
  }
#pragma unroll
  for (int o = 32; o; o >>= 1) sum += __shfl_xor(sum, o);
  __shared__ float red2[10];
  const int w = t >> 6, lane = t & 63;
  if (lane == 0) red2[w] = sum;
  __syncthreads();
  sum = 0.f;
#pragma unroll
  for (int i = 0; i < 10; ++i) sum += red2[i];
  const float sh = logf(sum);
#pragma unroll
  for (int i = 0; i < 6; ++i)
#pragma unroll
    for (int e = 0; e < 8; ++e) orow[(t + i * 640) * 8 + e] = v[i * 8 + e] - sh;
  if (extra)
#pragma unroll
    for (int e = 0; e < 8; ++e) orow[(3840 + t) * 8 + e] = v[48 + e] - sh;
}

extern "C" void kernel_launch(void* const* d_in, const int* in_sizes, int n_in,
                              void* d_out, int out_size, void* d_ws, size_t ws_size,
                              hipStream_t stream) {
  (void)in_sizes; (void)n_in; (void)out_size;
  if (ws_size < (size_t)212 * 1024 * 1024) return;

  const int* src = (const int*)d_in[0];
  const int* tgt = (const int*)d_in[1];
  const float* src_emb   = (const float*)d_in[4];
  const float* tgt_emb   = (const float*)d_in[5];
  const float* enc_attn_w = (const float*)d_in[6];
  const float* enc_attn_b = (const float*)d_in[7];
  const float* enc_ffn_w1 = (const float*)d_in[8];
  const float* enc_ffn_b1 = (const float*)d_in[9];
  const float* enc_ffn_w2 = (const float*)d_in[10];
  const float* enc_ffn_b2 = (const float*)d_in[11];
  const float* enc_ln_g  = (const float*)d_in[12];
  const float* enc_ln_b  = (const float*)d_in[13];
  const float* enc_norm_g = (const float*)d_in[14];
  const float* enc_norm_b = (const float*)d_in[15];
  const float* dec_self_w = (const float*)d_in[16];
  const float* dec_self_b = (const float*)d_in[17];
  const float* dec_cross_w = (const float*)d_in[18];
  const float* dec_cross_b = (const float*)d_in[19];
  const float* dec_ffn_w1 = (const float*)d_in[20];
  const float* dec_ffn_b1 = (const float*)d_in[21];
  const float* dec_ffn_w2 = (const float*)d_in[22];
  const float* dec_ffn_b2 = (const float*)d_in[23];
  const float* dec_ln_g  = (const float*)d_in[24];
  const float* dec_ln_b  = (const float*)d_in[25];
  const float* dec_norm_g = (const float*)d_in[26];
  const float* dec_norm_b = (const float*)d_in[27];
  const float* proj_w    = (const float*)d_in[28];
  const float* proj_b    = (const float*)d_in[29];

  char* ws = (char*)d_ws;
  auto MB = [](size_t x) { return x << 20; };
  // ws: [0,28) weight^T bufs, [28,59.25) proj_wt, [60,64) x_enc, [64,68) x_dec,
  // [68,70) hbuf, [70,72) enc_bf, [72,78) Qb/Kb/Vt, [78,80) attn_o, [80,205) logits,
  // [206,+1.25KB) cnt slices, [208,210) hbuf2.  ws >= 212 MB.
  bf16* enc_attn_wt  = (bf16*)(ws + MB(0));
  bf16* dec_self_wt  = (bf16*)(ws + MB(4));
  bf16* dec_cross_wt = (bf16*)(ws + MB(8));
  bf16* enc_f1t = (bf16*)(ws + MB(12));
  bf16* enc_f2t = (bf16*)(ws + MB(16));
  bf16* dec_f1t = (bf16*)(ws + MB(20));
  bf16* dec_f2t = (bf16*)(ws + MB(24));
  bf16* proj_wt = (bf16*)(ws + MB(28));
  float* x_enc  = (float*)(ws + MB(60));
  float* x_dec  = (float*)(ws + MB(64));
  bf16* hbuf    = (bf16*)(ws + MB(68));
  bf16* enc_bf  = (bf16*)(ws + MB(70));
  bf16* Qb      = (bf16*)(ws + MB(72));
  bf16* attn_o  = (bf16*)(ws + MB(78));
  bf16* logits  = (bf16*)(ws + MB(80));
  unsigned* cntbase = (unsigned*)(ws + MB(206));
  bf16* hbuf2   = (bf16*)(ws + MB(208));
  bf16* ffn_mid = (bf16*)d_out;

  // prep: all transposes + embed(+LN0) in one launch
  PrepArgs P;
  int acc = 0;
  auto setj = [&](int j, const float* s, bf16* d, int K, int N, int z) {
    P.tj.src[j] = s; P.tj.dst[j] = d; P.tj.K[j] = K; P.tj.N[j] = N; P.tj.ofs[j] = acc;
    acc += (K >> 5) * (N >> 5) * z;
  };
  setj(0, enc_attn_w, enc_attn_wt, 512, 512, 8);
  setj(1, dec_self_w, dec_self_wt, 512, 512, 8);
  setj(2, dec_cross_w, dec_cross_wt, 512, 512, 8);
  setj(3, enc_ffn_w1, enc_f1t, 512, 2048, 2);
  setj(4, enc_ffn_w2, enc_f2t, 2048, 512, 2);
  setj(5, dec_ffn_w1, dec_f1t, 512, 2048, 2);
  setj(6, dec_ffn_w2, dec_f2t, 2048, 512, 2);
  setj(7, proj_w, proj_wt, 512, 32000, 1);
  P.tj.ofs[8] = acc;
  P.ntile = acc;
  P.src = src; P.tgt = tgt;
  P.src_emb = src_emb; P.tgt_emb = tgt_emb;
  P.eg = enc_ln_g; P.eb = enc_ln_b;         // enc layer-0 LN1
  P.dg = dec_ln_g; P.db = dec_ln_b;         // dec layer-0 LN1
  P.x_enc = x_enc; P.x_dec = x_dec;
  P.hb_enc = hbuf; P.hb_dec = hbuf2;

  hipMemsetAsync(cntbase, 0, 1280, stream);
  k_prep<<<acc + 2 * kM, 256, 0, stream>>>(P);

  int slice = 0;
  auto out_proj_ln = [&](const bf16* wt, const float* bias, float* xio,
                         const float* lg, const float* lb, bf16* lnout) {
    k_gemm<64, 64, ST_F32, true, false, true, 3, false, false, true>
        <<<dim3(8, 32, 1), 256, 0, stream>>>(
        attn_o, 512, 0, wt + 3 * 262144, 512, 0, xio, 512, 0, 512, 1.f,
        bias + 3 * 512, xio, nullptr, lg, lb, lnout, cntbase + (slice++) * 32);
  };
  auto qkv = [&](const bf16* aptr, const bf16* wt, const float* bias, const bf16* kvA) {
    if (kvA)
      k_gemm<64, 64, ST_QKV, true, false, false, 3, false, true, false>
          <<<dim3(24, 32, 1), 256, 0, stream>>>(
          aptr, 512, 0, wt, 512, 0, Qb, 0, 0, 512, 1.f, bias, nullptr, kvA,
          nullptr, nullptr, nullptr, nullptr);
    else
      k_gemm<64, 64, ST_QKV, true, false, false, 3, false, false, false>
          <<<dim3(24, 32, 1), 256, 0, stream>>>(
          aptr, 512, 0, wt, 512, 0, Qb, 0, 0, 512, 1.f, bias, nullptr, nullptr,
          nullptr, nullptr, nullptr, nullptr);
  };
  auto fattn = [&](bool causal) {
    if (causal) k_fattn<true><<<dim3(16, kBH), 256, 0, stream>>>(Qb, Qb + 1048576, Qb + 2097152, attn_o);
    else        k_fattn<false><<<dim3(16, kBH), 256, 0, stream>>>(Qb, Qb + 1048576, Qb + 2097152, attn_o);
  };
  auto ffn = [&](float* xio, const bf16* w1t, const float* b1, const bf16* w2t,
                 const float* b2, const float* lg, const float* lb, bf16* lnout) {
    k_gemm<64, 64, ST_BF16, true, true, false, 3, false, false, false>
        <<<dim3(32, 32, 1), 256, 0, stream>>>(
        hbuf, 512, 0, w1t, 512, 0, ffn_mid, kF, 0, 512, 1.f, b1, nullptr, nullptr,
        nullptr, nullptr, nullptr, nullptr);
    k_gemm<64, 64, ST_F32, true, false, true, 3, false, false, true>
        <<<dim3(8, 32, 1), 256, 0, stream>>>(
        ffn_mid, 2048, 0, w2t, 2048, 0, xio, 512, 0, 2048, 1.f, b2, xio, nullptr,
        lg, lb, lnout, cntbase + (slice++) * 32);
  };

  // ---- encoder (hbuf holds LN'd input for the next consumer at each step)
  for (int i = 0; i < 2; ++i) {
    const bf16* wt = enc_attn_wt + (size_t)i * 1048576;
    const float* bias = enc_attn_b + i * 2048;
    qkv(hbuf, wt, bias, nullptr);
    fattn(false);
    out_proj_ln(wt, bias, x_enc, enc_ln_g + i * 1024 + 512, enc_ln_b + i * 1024 + 512, hbuf);
    const float* ng = (i == 0) ? enc_ln_g + 1024 : enc_norm_g;   // next LN params
    const float* nb = (i == 0) ? enc_ln_b + 1024 : enc_norm_b;
    bf16* nout = (i == 0) ? hbuf : enc_bf;
    ffn(x_enc, enc_f1t + (size_t)i * 1048576, enc_ffn_b1 + i * 2048,
        enc_f2t + (size_t)i * 1048576, enc_ffn_b2 + i * 512, ng, nb, nout);
  }

  // ---- decoder (dec l0 self-QKV reads hbuf2 from prep; thereafter hbuf)
  for (int i = 0; i < 2; ++i) {
    const bf16* wts = dec_self_wt + (size_t)i * 1048576;
    const float* bs = dec_self_b + i * 2048;
    const bf16* wtc = dec_cross_wt + (size_t)i * 1048576;
    const float* bc = dec_cross_b + i * 2048;
    qkv((i == 0) ? hbuf2 : hbuf, wts, bs, nullptr);
    fattn(true);
    out_proj_ln(wts, bs, x_dec, dec_ln_g + i * 1536 + 512, dec_ln_b + i * 1536 + 512, hbuf);
    qkv(hbuf, wtc, bc, enc_bf);
    fattn(false);
    out_proj_ln(wtc, bc, x_dec, dec_ln_g + i * 1536 + 1024, dec_ln_b + i * 1536 + 1024, hbuf);
    const float* ng = (i == 0) ? dec_ln_g + 1536 : dec_norm_g;
    const float* nb = (i == 0) ? dec_ln_b + 1536 : dec_norm_b;
    ffn(x_dec, dec_f1t + (size_t)i * 1048576, dec_ffn_b1 + i * 2048,
        dec_f2t + (size_t)i * 1048576, dec_ffn_b2 + i * 512, ng, nb, hbuf);
    (void)ng; (void)nb;
  }

  // logits -> log_softmax
  k_proj256<<<dim3(125, 8), 512, 0, stream>>>(hbuf, proj_wt, logits, proj_b);
  k_lsm_bf<<<kM, 640, 0, stream>>>(logits, (float*)d_out);
}

// Round 15
// 675.164 us; speedup vs baseline: 1.5268x; 1.5268x over previous
//
#include <hip/hip_runtime.h>
#include <hip/hip_bf16.h>
#include <math.h>

using bf16 = __hip_bfloat16;
typedef float f32x4 __attribute__((ext_vector_type(4)));
typedef short short8 __attribute__((ext_vector_type(8)));

constexpr int kD = 512, kH = 8, kDk = 64, kF = 2048, kV = 32000;
constexpr int kB = 2, kS = 1024, kM = 2048, kBH = 16;  // kM = B*S tokens

enum { ST_F32 = 0, ST_BF16, ST_QKV };

__device__ __forceinline__ void gload_lds16(const void* g, void* l) {
  __builtin_amdgcn_global_load_lds(
      (const __attribute__((address_space(1))) void*)g,
      (__attribute__((address_space(3))) void*)l, 16, 0, 0);
}

__device__ __forceinline__ float bfu2f(short u) {
  union { unsigned int i; float f; } c;
  c.i = ((unsigned int)(unsigned short)u) << 16;
  return c.f;
}

// ---------------- generic MFMA GEMM: C = A[M,K] @ Bt[N,K]^T (+bias)(+relu)(+res)
// BMxBN tiles, 4 waves (2x2), 3-deep counted-vmcnt pipeline, XOR-swizzled LDS (R13).
// R15: BM=32 variant (grid 2x blocks -> 2 blocks/CU TLP) for the latency-bound
// out_proj/ffn2 sites; ledger parameterized on LPS = loads/stage (3 -> vmcnt(6)).
template <int BM, int BN, int STM, bool BIAS, bool RELU, bool RES, int NBUF, bool XSWZ, bool ASEL>
__launch_bounds__(256)
__global__ void k_gemm(const bf16* __restrict__ A, int lda, long long Az,
                       const bf16* __restrict__ Bt, int ldb, long long Bz,
                       void* __restrict__ Cv, int ldc, long long Cz,
                       int K, float alpha,
                       const float* __restrict__ bias,
                       const float* __restrict__ res,
                       const bf16* __restrict__ A2) {
  constexpr int FM = BM / 32, FN = BN / 32;
  constexpr int LPS = BM / 32 + BN / 32;   // global_load_lds per stage
  __shared__ __attribute__((aligned(16))) bf16 As[NBUF][BM * 64];
  __shared__ __attribute__((aligned(16))) bf16 Bs[NBUF][BN * 64];
  const int tid = threadIdx.x;
  const int w = tid >> 6, lane = tid & 63;
  int bx = blockIdx.x, by = blockIdx.y;
  if constexpr (XSWZ) {
    const int nx = gridDim.x, ny = gridDim.y;
    const int lin = by * nx + bx;
    const int cpx = (nx * ny) >> 3;
    const int s = (lin & 7) * cpx + (lin >> 3);
    bx = s / ny;
    by = s - bx * ny;
  }
  const int bm = by * BM, bn = bx * BN;
  const int z = blockIdx.z;
  if constexpr (ASEL) { if (bn >= 512) A = A2; }
  A += (long long)z * Az;
  Bt += (long long)z * Bz;
  const int l15 = lane & 15, lhi = lane >> 4;
  const int wr = (w >> 1) * (BM / 2), wc = (w & 1) * (BN / 2);
  f32x4 acc[FM][FN] = {};
  const int nkt = K >> 6;  // BK = 64

  auto stage = [&](int kt, int nb) {
#pragma unroll
    for (int it = 0; it < BM / 32; ++it) {
      int chunk = (it * 4 + w) * 64 + lane;        // 16B chunks, LDS-linear dest
      int row = chunk >> 3, c = chunk & 7;
      int col = (c ^ (row & 7)) << 3;              // pre-swizzled global source
      gload_lds16(A + (size_t)(bm + row) * lda + kt * 64 + col, As[nb] + (it * 4 + w) * 512);
    }
#pragma unroll
    for (int it = 0; it < BN / 32; ++it) {
      int chunk = (it * 4 + w) * 64 + lane;
      int row = chunk >> 3, c = chunk & 7;
      int col = (c ^ (row & 7)) << 3;
      gload_lds16(Bt + (size_t)(bn + row) * ldb + kt * 64 + col, Bs[nb] + (it * 4 + w) * 512);
    }
  };
  auto waitSteady = [&]() {
    if constexpr (LPS == 3) asm volatile("s_waitcnt vmcnt(6)" ::: "memory");
    else                    asm volatile("s_waitcnt vmcnt(8)" ::: "memory");
  };
  auto compute = [&](int cb) {
#pragma unroll
    for (int kk = 0; kk < 2; ++kk) {
      short8 af[FM], bf[FN];
#pragma unroll
      for (int i = 0; i < FM; ++i) {
        int row = wr + i * 16 + l15;
        af[i] = *(const short8*)(As[cb] + row * 64 + (((kk * 4 + lhi) ^ (row & 7)) * 8));
      }
#pragma unroll
      for (int j = 0; j < FN; ++j) {
        int row = wc + j * 16 + l15;
        bf[j] = *(const short8*)(Bs[cb] + row * 64 + (((kk * 4 + lhi) ^ (row & 7)) * 8));
      }
#pragma unroll
      for (int i = 0; i < FM; ++i)
#pragma unroll
        for (int j = 0; j < FN; ++j)
          acc[i][j] = __builtin_amdgcn_mfma_f32_16x16x32_bf16(af[i], bf[j], acc[i][j], 0, 0, 0);
    }
  };

  if constexpr (NBUF == 3) {
    stage(0, 0);
    stage(1, 1);
    stage(2, 2);                                   // 3*LPS loads out
    waitSteady();                                  // tile0 landed
    __builtin_amdgcn_s_barrier();
    __builtin_amdgcn_sched_barrier(0);
    int cur = 0;
    for (int kt = 0; kt < nkt; ++kt) {
      compute(cur);
      asm volatile("s_waitcnt lgkmcnt(0)" ::: "memory");  // ds_reads of buf[cur] done
      __builtin_amdgcn_sched_barrier(0);
      if (kt + 1 < nkt) {
        __builtin_amdgcn_s_barrier();        // all waves done reading buf[cur]
        if (kt + 3 < nkt) {
          stage(kt + 3, cur);                // overwrite buf[cur]
          waitSteady();                      // stage(kt+1) landed
        } else {
          asm volatile("s_waitcnt vmcnt(0)" ::: "memory");
        }
        __builtin_amdgcn_s_barrier();        // all waves confirm next buf ready
        __builtin_amdgcn_sched_barrier(0);
      }
      cur = (cur == 2) ? 0 : cur + 1;
    }
  } else {
    for (int kt = 0; kt < nkt; ++kt) {
      stage(kt, 0);
      __syncthreads();
      compute(0);
      __syncthreads();
    }
  }

  // epilogue: C/D layout col=lane&15, row=(lane>>4)*4+r (m89-verified)
#pragma unroll
  for (int i = 0; i < FM; ++i) {
#pragma unroll
    for (int j = 0; j < FN; ++j) {
#pragma unroll
      for (int r = 0; r < 4; ++r) {
        int m = bm + wr + i * 16 + lhi * 4 + r;
        int n = bn + wc + j * 16 + l15;
        float val = acc[i][j][r] * alpha;
        if constexpr (BIAS) val += bias[n];
        if constexpr (RELU) val = fmaxf(val, 0.f);
        if constexpr (RES) val += res[(size_t)m * ldc + n];
        if constexpr (STM == ST_F32) {
          ((float*)Cv)[(size_t)z * Cz + (size_t)m * ldc + n] = val;
        } else if constexpr (STM == ST_BF16) {
          ((bf16*)Cv)[(size_t)z * Cz + (size_t)m * ldc + n] = __float2bfloat16(val);
        } else if constexpr (STM == ST_QKV) {    // n<512->Q, <1024->K (both [B,H,S,dk]), else V^T [B,H,dk,S]
          int seg = n >> 9, nn = n & 511;
          int b_ = m >> 10, s_ = m & 1023, h_ = nn >> 6, d_ = nn & 63;
          size_t idx = (seg < 2)
              ? (((size_t)(b_ * kH + h_) << 10) + s_) * kDk + d_
              : ((size_t)(b_ * kH + h_) * kDk + d_) * kS + s_;
          ((bf16*)Cv)[(size_t)seg * 1048576 + idx] = __float2bfloat16(val);
        }
      }
    }
  }
}

// ---------------- fused flash attention (unchanged from R13)
template <bool CAUSAL>
__launch_bounds__(256)
__global__ void k_fattn(const bf16* __restrict__ Q, const bf16* __restrict__ K,
                        const bf16* __restrict__ Vt, bf16* __restrict__ O) {
  __shared__ __attribute__((aligned(16))) bf16 Ks[3][4096];
  __shared__ __attribute__((aligned(16))) bf16 Vs[3][4096];
  __shared__ __attribute__((aligned(16))) bf16 Ps[4][1024];
  const int tid = threadIdx.x, w = tid >> 6, lane = tid & 63;
  const int l15 = lane & 15, lhi = lane >> 4;
  const int q0 = blockIdx.x * 64, bh = blockIdx.y;
  const int qw = q0 + w * 16;
  const bf16* Qp = Q + (((size_t)(bh << 10)) + qw + l15) * kDk;
  short8 aq[2];
  aq[0] = *(const short8*)(Qp + lhi * 8);
  aq[1] = *(const short8*)(Qp + 32 + lhi * 8);
  const int srow = w * 8 + (lane >> 3);
  const int sc = (lane & 7) ^ (srow & 7);
  const bf16* Ksrc = K + (((size_t)(bh << 10)) + srow) * kDk + sc * 8;
  const bf16* Vsrc = Vt + ((size_t)bh * kDk + srow) * kS + sc * 8;
  const int nt = CAUSAL ? (q0 >> 6) + 1 : (kS >> 6);

  auto stage = [&](int t, int nb) {
    int kv0 = t << 6;
    gload_lds16(Ksrc + (size_t)kv0 * kDk, Ks[nb] + w * 512);
    gload_lds16(Ksrc + (size_t)(kv0 + 32) * kDk, Ks[nb] + 2048 + w * 512);
    gload_lds16(Vsrc + kv0, Vs[nb] + w * 512);
    gload_lds16(Vsrc + kv0 + 32 * kS, Vs[nb] + 2048 + w * 512);
  };

  float m_[4], l_[4];
#pragma unroll
  for (int r = 0; r < 4; ++r) { m_[r] = -1e30f; l_[r] = 0.f; }
  f32x4 ao[4] = {};

  stage(0, 0);
  if (nt > 2) {
    stage(1, 1);
    stage(2, 2);
    asm volatile("s_waitcnt vmcnt(8)" ::: "memory");
  } else if (nt > 1) {
    stage(1, 1);
    asm volatile("s_waitcnt vmcnt(4)" ::: "memory");
  } else {
    asm volatile("s_waitcnt vmcnt(0)" ::: "memory");
  }
  __builtin_amdgcn_s_barrier();
  __builtin_amdgcn_sched_barrier(0);

  int cur = 0;
  for (int t = 0; t < nt; ++t) {
    f32x4 as[4] = {};
#pragma unroll
    for (int kk = 0; kk < 2; ++kk) {
      short8 bk[4];
#pragma unroll
      for (int nf = 0; nf < 4; ++nf) {
        int row = nf * 16 + l15;
        int c = (4 * kk + lhi) ^ (row & 7);
        bk[nf] = *(const short8*)(Ks[cur] + row * 64 + c * 8);
      }
#pragma unroll
      for (int nf = 0; nf < 4; ++nf)
        as[nf] = __builtin_amdgcn_mfma_f32_16x16x32_bf16(aq[kk], bk[nf], as[nf], 0, 0, 0);
    }
    float s[4][4];
#pragma unroll
    for (int nf = 0; nf < 4; ++nf)
#pragma unroll
      for (int r = 0; r < 4; ++r) {
        float v = as[nf][r] * 0.125f;
        if (CAUSAL && t == nt - 1) {
          int col = (t << 6) + nf * 16 + l15;
          int row = qw + lhi * 4 + r;
          if (col > row) v = -1e30f;
        }
        s[nf][r] = v;
      }
    float mn[4], scl[4], rsum[4];
#pragma unroll
    for (int r = 0; r < 4; ++r) {
      float mx = fmaxf(fmaxf(s[0][r], s[1][r]), fmaxf(s[2][r], s[3][r]));
      mx = fmaxf(mx, __shfl_xor(mx, 1));
      mx = fmaxf(mx, __shfl_xor(mx, 2));
      mx = fmaxf(mx, __shfl_xor(mx, 4));
      mx = fmaxf(mx, __shfl_xor(mx, 8));
      mn[r] = fmaxf(m_[r], mx);
      scl[r] = __expf(m_[r] - mn[r]);
      rsum[r] = 0.f;
    }
#pragma unroll
    for (int nf = 0; nf < 4; ++nf)
#pragma unroll
      for (int r = 0; r < 4; ++r) {
        float p = __expf(s[nf][r] - mn[r]);
        rsum[r] += p;
        int pr = lhi * 4 + r;
        int c = (2 * nf + (l15 >> 3)) ^ (pr & 7);
        Ps[w][pr * 64 + c * 8 + (l15 & 7)] = __float2bfloat16(p);
      }
#pragma unroll
    for (int r = 0; r < 4; ++r) {
      float su = rsum[r];
      su += __shfl_xor(su, 1);
      su += __shfl_xor(su, 2);
      su += __shfl_xor(su, 4);
      su += __shfl_xor(su, 8);
      l_[r] = l_[r] * scl[r] + su;
      m_[r] = mn[r];
    }
#pragma unroll
    for (int nf = 0; nf < 4; ++nf)
#pragma unroll
      for (int r = 0; r < 4; ++r) ao[nf][r] *= scl[r];
    asm volatile("s_waitcnt lgkmcnt(0)" ::: "memory");
    __builtin_amdgcn_sched_barrier(0);
#pragma unroll
    for (int kk = 0; kk < 2; ++kk) {
      short8 pa = *(const short8*)(Ps[w] + l15 * 64 + (((4 * kk + lhi) ^ (l15 & 7)) * 8));
      short8 bv[4];
#pragma unroll
      for (int nf = 0; nf < 4; ++nf) {
        int row = nf * 16 + l15;
        int c = (4 * kk + lhi) ^ (row & 7);
        bv[nf] = *(const short8*)(Vs[cur] + row * 64 + c * 8);
      }
#pragma unroll
      for (int nf = 0; nf < 4; ++nf)
        ao[nf] = __builtin_amdgcn_mfma_f32_16x16x32_bf16(pa, bv[nf], ao[nf], 0, 0, 0);
    }
    asm volatile("s_waitcnt lgkmcnt(0)" ::: "memory");
    __builtin_amdgcn_sched_barrier(0);
    if (t + 1 < nt) {
      __builtin_amdgcn_s_barrier();
      if (t + 3 < nt) {
        stage(t + 3, cur);
        asm volatile("s_waitcnt vmcnt(8)" ::: "memory");
      } else {
        asm volatile("s_waitcnt vmcnt(0)" ::: "memory");
      }
      __builtin_amdgcn_s_barrier();
      __builtin_amdgcn_sched_barrier(0);
    }
    cur = (cur == 2) ? 0 : cur + 1;
  }
  const int b_ = bh >> 3, h_ = bh & 7;
  float inv[4];
#pragma unroll
  for (int r = 0; r < 4; ++r) inv[r] = 1.f / l_[r];
#pragma unroll
  for (int nf = 0; nf < 4; ++nf)
#pragma unroll
    for (int r = 0; r < 4; ++r) {
      int q = qw + lhi * 4 + r;
      O[((size_t)(b_ * kS + q)) * kD + h_ * kDk + nf * 16 + l15] =
          __float2bfloat16(ao[nf][r] * inv[r]);
    }
}

// ---------------- batched fp32 [K,N] -> bf16 transposed [N,K], 8 jobs in one launch
struct TJobs {
  const float* src[8];
  bf16* dst[8];
  int K[8], N[8];
  int ofs[9];
};

__global__ void k_transpose_all(TJobs J) {
  __shared__ float t[32][33];
  const int tb = blockIdx.x;
  int j = 0;
#pragma unroll
  for (int i = 1; i < 8; ++i) j += (tb >= J.ofs[i]) ? 1 : 0;
  const int K = J.K[j], N = J.N[j];
  const int tn = N >> 5, tk = K >> 5;
  int r = tb - J.ofs[j];
  const int z = r / (tn * tk);
  r -= z * tn * tk;
  const int k0 = (r / tn) << 5, n0 = (r % tn) << 5;
  const float* Wp = J.src[j] + (size_t)z * K * N;
  bf16* WTp = J.dst[j] + (size_t)z * K * N;
  const int tx = threadIdx.x, ty = threadIdx.y;  // (32,8)
#pragma unroll
  for (int rr = 0; rr < 32; rr += 8) t[ty + rr][tx] = Wp[(size_t)(k0 + ty + rr) * N + n0 + tx];
  __syncthreads();
#pragma unroll
  for (int rr = 0; rr < 32; rr += 8)
    WTp[(size_t)(n0 + ty + rr) * K + k0 + tx] = __float2bfloat16(t[tx][ty + rr]);
}

// ---------------- embedding * sqrt(D) + positional encoding (fp32 out), both streams
__global__ void k_embed2(const int* __restrict__ src, const int* __restrict__ tgt,
                         const float* __restrict__ se, const float* __restrict__ te,
                         float* __restrict__ xe, float* __restrict__ xd) {
  const int m = blockIdx.x, which = blockIdx.y;
  const int* tok = which ? tgt : src;
  const float* emb = which ? te : se;
  float* x = which ? xd : xe;
  int s = m & (kS - 1);
  const float* e = emb + (size_t)tok[m] * kD;
  float* xp = x + (size_t)m * kD;
  for (int d = threadIdx.x; d < kD; d += 256) {
    int i = d >> 1;
    float freq = __expf(-(float)(2 * i) * (9.210340371976184f / 512.0f));
    float ang = (float)s * freq;
    float pe = (d & 1) ? cosf(ang) : sinf(ang);
    xp[d] = e[d] * 22.62741699796952f + pe;
  }
}

// ---------------- LayerNorm (unbiased var /511, eps 1e-6), fp32 in -> bf16 out. wave/row.
__global__ void k_ln(const float* __restrict__ x, const float* __restrict__ g,
                     const float* __restrict__ b, bf16* __restrict__ out) {
  int w = threadIdx.x >> 6, lane = threadIdx.x & 63;
  int row = blockIdx.x * 4 + w;
  const float* xp = x + (size_t)row * kD;
  float v[8];
  float sum = 0.f;
#pragma unroll
  for (int i = 0; i < 8; ++i) { v[i] = xp[lane + i * 64]; sum += v[i]; }
#pragma unroll
  for (int o = 32; o; o >>= 1) sum += __shfl_xor(sum, o);
  float mean = sum * (1.f / 512.f);
  float sq = 0.f;
#pragma unroll
  for (int i = 0; i < 8; ++i) { float d = v[i] - mean; sq += d * d; }
#pragma unroll
  for (int o = 32; o; o >>= 1) sq += __shfl_xor(sq, o);
  float inv = rsqrtf(sq * (1.f / 511.f) + 1e-6f);
  bf16* op = out + (size_t)row * kD;
#pragma unroll
  for (int i = 0; i < 8; ++i) {
    int d = lane + i * 64;
    op[d] = __float2bfloat16(g[d] * (v[i] - mean) * inv + b[d]);
  }
}

// ---------------- 256^2-tile proj GEMM (unchanged)
__global__ __launch_bounds__(512, 1) void k_proj256(const bf16* __restrict__ A,
                                                    const bf16* __restrict__ Bt,
                                                    bf16* __restrict__ C,
                                                    const float* __restrict__ bias) {
  __shared__ __attribute__((aligned(16))) bf16 As[4][256 * 32];
  __shared__ __attribute__((aligned(16))) bf16 Bs[4][256 * 32];
  const int tid = threadIdx.x, w = tid >> 6, lane = tid & 63;
  const int l15 = lane & 15, lhi = lane >> 4;
  const int lin = blockIdx.y * 125 + blockIdx.x;
  const int s = (lin & 7) * 125 + (lin >> 3);
  const int bx = s >> 3, by = s & 7;
  const int bm = by * 256, bn = bx * 256;
  const int wr = (w >> 2) * 128, wc = (w & 3) * 64;
  const int rowq = tid >> 2, chk = tid & 3;
  const int swz = (chk ^ ((rowq >> 1) & 3)) << 3;
  const bf16* Asrc0 = A + (size_t)(bm + rowq) * kD + swz;
  const bf16* Asrc1 = A + (size_t)(bm + 128 + rowq) * kD + swz;
  const bf16* Bsrc0 = Bt + (size_t)(bn + rowq) * kD + swz;
  const bf16* Bsrc1 = Bt + (size_t)(bn + 128 + rowq) * kD + swz;
  const int ldsoff = w * 1024;

  auto stage = [&](int kt) {
    const int b = kt & 3;
    const int ko = kt * 32;
    gload_lds16(Asrc0 + ko, (char*)As[b] + ldsoff);
    gload_lds16(Asrc1 + ko, (char*)As[b] + 8192 + ldsoff);
    gload_lds16(Bsrc0 + ko, (char*)Bs[b] + ldsoff);
    gload_lds16(Bsrc1 + ko, (char*)Bs[b] + 8192 + ldsoff);
  };

  const int ra = wr + l15, rb = wc + l15;
  const int abase = ra * 64 + ((lhi ^ ((ra >> 1) & 3)) << 4);
  const int bbase = rb * 64 + ((lhi ^ ((rb >> 1) & 3)) << 4);

  f32x4 acc[8][4] = {};
  stage(0); stage(1); stage(2);
  for (int kt = 0; kt < 16; ++kt) {
    if (kt + 2 < 16)      asm volatile("s_waitcnt vmcnt(8)" ::: "memory");
    else if (kt + 1 < 16) asm volatile("s_waitcnt vmcnt(4)" ::: "memory");
    else                  asm volatile("s_waitcnt vmcnt(0)" ::: "memory");
    __builtin_amdgcn_s_barrier();
    __builtin_amdgcn_sched_barrier(0);
    if (kt + 3 < 16) stage(kt + 3);
    const int b = kt & 3;
    short8 af[8], bf[4];
#pragma unroll
    for (int i = 0; i < 8; ++i)
      af[i] = *(const short8*)((const char*)As[b] + abase + i * 1024);
#pragma unroll
    for (int j = 0; j < 4; ++j)
      bf[j] = *(const short8*)((const char*)Bs[b] + bbase + j * 1024);
#pragma unroll
    for (int i = 0; i < 8; ++i)
#pragma unroll
      for (int j = 0; j < 4; ++j)
        acc[i][j] = __builtin_amdgcn_mfma_f32_16x16x32_bf16(af[i], bf[j], acc[i][j], 0, 0, 0);
    asm volatile("s_waitcnt lgkmcnt(0)" ::: "memory");
    __builtin_amdgcn_sched_barrier(0);
  }
#pragma unroll
  for (int i = 0; i < 8; ++i)
#pragma unroll
    for (int j = 0; j < 4; ++j)
#pragma unroll
      for (int r = 0; r < 4; ++r) {
        int m = bm + wr + i * 16 + lhi * 4 + r;
        int n = bn + wc + j * 16 + l15;
        C[(size_t)m * kV + n] = __float2bfloat16(acc[i][j][r] + bias[n]);
      }
}

// ---------------- log_softmax: bf16 logits -> fp32 out (unchanged)
__global__ __launch_bounds__(640, 2) void k_lsm_bf(const bf16* __restrict__ L,
                                                   float* __restrict__ y) {
  const bf16* row = L + (size_t)blockIdx.x * kV;
  float* orow = y + (size_t)blockIdx.x * kV;
  const int t = threadIdx.x;
  const bool extra = t < 160;
  float v[56];
  float sum = 0.f;
#pragma unroll
  for (int i = 0; i < 6; ++i) {
    short8 s = *(const short8*)(row + (t + i * 640) * 8);
#pragma unroll
    for (int e = 0; e < 8; ++e) {
      float f = bfu2f(s[e]);
      v[i * 8 + e] = f;
      sum += __expf(f);
    }
  }
  if (extra) {
    short8 s = *(const short8*)(row + (3840 + t) * 8);
#pragma unroll
    for (int e = 0; e < 8; ++e) {
      float f = bfu2f(s[e]);
      v[48 + e] = f;
      sum += __expf(f);
    }
  }
#pragma unroll
  for (int o = 32; o; o >>= 1) sum += __shfl_xor(sum, o);
  __shared__ float red2[10];
  const int w = t >> 6, lane = t & 63;
  if (lane == 0) red2[w] = sum;
  __syncthreads();
  sum = 0.f;
#pragma unroll
  for (int i = 0; i < 10; ++i) sum += red2[i];
  const float sh = logf(sum);
#pragma unroll
  for (int i = 0; i < 6; ++i)
#pragma unroll
    for (int e = 0; e < 8; ++e) orow[(t + i * 640) * 8 + e] = v[i * 8 + e] - sh;
  if (extra)
#pragma unroll
    for (int e = 0; e < 8; ++e) orow[(3840 + t) * 8 + e] = v[48 + e] - sh;
}

extern "C" void kernel_launch(void* const* d_in, const int* in_sizes, int n_in,
                              void* d_out, int out_size, void* d_ws, size_t ws_size,
                              hipStream_t stream) {
  (void)in_sizes; (void)n_in; (void)out_size;
  if (ws_size < (size_t)212 * 1024 * 1024) return;

  const int* src = (const int*)d_in[0];
  const int* tgt = (const int*)d_in[1];
  const float* src_emb   = (const float*)d_in[4];
  const float* tgt_emb   = (const float*)d_in[5];
  const float* enc_attn_w = (const float*)d_in[6];
  const float* enc_attn_b = (const float*)d_in[7];
  const float* enc_ffn_w1 = (const float*)d_in[8];
  const float* enc_ffn_b1 = (const float*)d_in[9];
  const float* enc_ffn_w2 = (const float*)d_in[10];
  const float* enc_ffn_b2 = (const float*)d_in[11];
  const float* enc_ln_g  = (const float*)d_in[12];
  const float* enc_ln_b  = (const float*)d_in[13];
  const float* enc_norm_g = (const float*)d_in[14];
  const float* enc_norm_b = (const float*)d_in[15];
  const float* dec_self_w = (const float*)d_in[16];
  const float* dec_self_b = (const float*)d_in[17];
  const float* dec_cross_w = (const float*)d_in[18];
  const float* dec_cross_b = (const float*)d_in[19];
  const float* dec_ffn_w1 = (const float*)d_in[20];
  const float* dec_ffn_b1 = (const float*)d_in[21];
  const float* dec_ffn_w2 = (const float*)d_in[22];
  const float* dec_ffn_b2 = (const float*)d_in[23];
  const float* dec_ln_g  = (const float*)d_in[24];
  const float* dec_ln_b  = (const float*)d_in[25];
  const float* dec_norm_g = (const float*)d_in[26];
  const float* dec_norm_b = (const float*)d_in[27];
  const float* proj_w    = (const float*)d_in[28];
  const float* proj_b    = (const float*)d_in[29];

  char* ws = (char*)d_ws;
  auto MB = [](size_t x) { return x << 20; };
  bf16* enc_attn_wt  = (bf16*)(ws + MB(0));
  bf16* dec_self_wt  = (bf16*)(ws + MB(4));
  bf16* dec_cross_wt = (bf16*)(ws + MB(8));
  bf16* enc_f1t = (bf16*)(ws + MB(12));
  bf16* enc_f2t = (bf16*)(ws + MB(16));
  bf16* dec_f1t = (bf16*)(ws + MB(20));
  bf16* dec_f2t = (bf16*)(ws + MB(24));
  bf16* proj_wt = (bf16*)(ws + MB(28));
  float* x_enc  = (float*)(ws + MB(60));
  float* x_dec  = (float*)(ws + MB(64));
  bf16* hbuf    = (bf16*)(ws + MB(68));
  bf16* enc_bf  = (bf16*)(ws + MB(70));
  bf16* Qb      = (bf16*)(ws + MB(72));  // Kb at +1Mi elems, VtB at +2Mi
  bf16* attn_o  = (bf16*)(ws + MB(78));
  bf16* logits  = (bf16*)(ws + MB(80));  // 131 MB, up to MB(211)
  bf16* ffn_mid = (bf16*)d_out;          // d_out free until final projection

  // ---- all weight transposes in one launch
  TJobs tj;
  int acc = 0;
  auto setj = [&](int j, const float* s, bf16* d, int K, int N, int z) {
    tj.src[j] = s; tj.dst[j] = d; tj.K[j] = K; tj.N[j] = N; tj.ofs[j] = acc;
    acc += (K >> 5) * (N >> 5) * z;
  };
  setj(0, enc_attn_w, enc_attn_wt, 512, 512, 8);
  setj(1, dec_self_w, dec_self_wt, 512, 512, 8);
  setj(2, dec_cross_w, dec_cross_wt, 512, 512, 8);
  setj(3, enc_ffn_w1, enc_f1t, 512, 2048, 2);
  setj(4, enc_ffn_w2, enc_f2t, 2048, 512, 2);
  setj(5, dec_ffn_w1, dec_f1t, 512, 2048, 2);
  setj(6, dec_ffn_w2, dec_f2t, 2048, 512, 2);
  setj(7, proj_w, proj_wt, 512, 32000, 1);
  tj.ofs[8] = acc;
  k_transpose_all<<<acc, dim3(32, 8), 0, stream>>>(tj);

  k_embed2<<<dim3(kM, 2), 256, 0, stream>>>(src, tgt, src_emb, tgt_emb, x_enc, x_dec);

  auto LN = [&](const float* x, const float* g, const float* b, bf16* out) {
    k_ln<<<kM / 4, 256, 0, stream>>>(x, g, b, out);
  };
  // R15: BM=32 (grid 8x64 = 2 blocks/CU) for the latency-bound out_proj / ffn2
  auto out_proj = [&](const bf16* wt, const float* bias, float* xio) {
    k_gemm<32, 64, ST_F32, true, false, true, 3, false, false><<<dim3(8, 64, 1), 256, 0, stream>>>(
        attn_o, 512, 0, wt + 3 * 262144, 512, 0, xio, 512, 0, 512, 1.f, bias + 3 * 512, xio, nullptr);
  };
  auto self_attn = [&](const bf16* wt, const float* bias, bool causal, float* xio) {
    k_gemm<64, 64, ST_QKV, true, false, false, 3, false, false><<<dim3(24, 32, 1), 256, 0, stream>>>(
        hbuf, 512, 0, wt, 512, 0, Qb, 0, 0, 512, 1.f, bias, nullptr, nullptr);
    if (causal) k_fattn<true><<<dim3(16, kBH), 256, 0, stream>>>(Qb, Qb + 1048576, Qb + 2097152, attn_o);
    else        k_fattn<false><<<dim3(16, kBH), 256, 0, stream>>>(Qb, Qb + 1048576, Qb + 2097152, attn_o);
    out_proj(wt, bias, xio);
  };
  // cross-attn: single QKV launch; blocks with bn<512 (Q) read hbuf, bn>=512 (K,V) read enc_bf
  auto cross_attn = [&](const bf16* wt, const float* bias, float* xio) {
    k_gemm<64, 64, ST_QKV, true, false, false, 3, false, true><<<dim3(24, 32, 1), 256, 0, stream>>>(
        hbuf, 512, 0, wt, 512, 0, Qb, 0, 0, 512, 1.f, bias, nullptr, enc_bf);
    k_fattn<false><<<dim3(16, kBH), 256, 0, stream>>>(Qb, Qb + 1048576, Qb + 2097152, attn_o);
    out_proj(wt, bias, xio);
  };
  auto ffn_block = [&](float* xio, const bf16* w1t, const float* b1, const bf16* w2t,
                       const float* b2, const float* g, const float* bl) {
    LN(xio, g, bl, hbuf);
    k_gemm<64, 64, ST_BF16, true, true, false, 3, false, false><<<dim3(32, 32, 1), 256, 0, stream>>>(
        hbuf, 512, 0, w1t, 512, 0, ffn_mid, kF, 0, 512, 1.f, b1, nullptr, nullptr);
    k_gemm<32, 64, ST_F32, true, false, true, 3, false, false><<<dim3(8, 64, 1), 256, 0, stream>>>(
        ffn_mid, 2048, 0, w2t, 2048, 0, xio, 512, 0, 2048, 1.f, b2, xio, nullptr);
  };

  // encoder
  for (int i = 0; i < 2; ++i) {
    LN(x_enc, enc_ln_g + i * 1024, enc_ln_b + i * 1024, hbuf);
    self_attn(enc_attn_wt + (size_t)i * 1048576, enc_attn_b + i * 2048, false, x_enc);
    ffn_block(x_enc, enc_f1t + (size_t)i * 1048576, enc_ffn_b1 + i * 2048,
              enc_f2t + (size_t)i * 1048576, enc_ffn_b2 + i * 512,
              enc_ln_g + i * 1024 + 512, enc_ln_b + i * 1024 + 512);
  }
  LN(x_enc, enc_norm_g, enc_norm_b, enc_bf);

  // decoder
  for (int i = 0; i < 2; ++i) {
    LN(x_dec, dec_ln_g + i * 1536, dec_ln_b + i * 1536, hbuf);
    self_attn(dec_self_wt + (size_t)i * 1048576, dec_self_b + i * 2048, true, x_dec);
    LN(x_dec, dec_ln_g + i * 1536 + 512, dec_ln_b + i * 1536 + 512, hbuf);
    cross_attn(dec_cross_wt + (size_t)i * 1048576, dec_cross_b + i * 2048, x_dec);
    ffn_block(x_dec, dec_f1t + (size_t)i * 1048576, dec_ffn_b1 + i * 2048,
              dec_f2t + (size_t)i * 1048576, dec_ffn_b2 + i * 512,
              dec_ln_g + i * 1536 + 1024, dec_ln_b + i * 1536 + 1024);
  }
  LN(x_dec, dec_norm_g, dec_norm_b, hbuf);

  // logits (bf16, to ws) via 256^2 deep-pipelined GEMM -> log_softmax -> fp32 d_out
  k_proj256<<<dim3(125, 8), 512, 0, stream>>>(hbuf, proj_wt, logits, proj_b);
  k_lsm_bf<<<kM, 640, 0, stream>>>(logits, (float*)d_out);
}

// Round 16
// 662.350 us; speedup vs baseline: 1.5564x; 1.0193x over previous
//
#include <hip/hip_runtime.h>
#include <hip/hip_bf16.h>
#include <math.h>

using bf16 = __hip_bfloat16;
typedef float f32x4 __attribute__((ext_vector_type(4)));
typedef short short8 __attribute__((ext_vector_type(8)));

constexpr int kD = 512, kH = 8, kDk = 64, kF = 2048, kV = 32000;
constexpr int kB = 2, kS = 1024, kM = 2048, kBH = 16;  // kM = B*S tokens

enum { ST_F32 = 0, ST_BF16, ST_QKV };

__device__ __forceinline__ void gload_lds16(const void* g, void* l) {
  __builtin_amdgcn_global_load_lds(
      (const __attribute__((address_space(1))) void*)g,
      (__attribute__((address_space(3))) void*)l, 16, 0, 0);
}

__device__ __forceinline__ float bfu2f(short u) {
  union { unsigned int i; float f; } c;
  c.i = ((unsigned int)(unsigned short)u) << 16;
  return c.f;
}

// ---------------- generic MFMA GEMM: C = A[M,K] @ Bt[N,K]^T (+bias)(+relu)(+res)
// BMxBN tiles, 4 waves (2x2), 3-deep counted-vmcnt pipeline, XOR-swizzled LDS (R13).
// DUAL (R16): grid.y doubled; upper half switches {A,Bt,Cv,bias,res} to job 2
// (merges two independent same-shape GEMMs into one launch, cuts launch gaps).
// ASEL: blocks with bn>=512 read A2 (cross-attn Q/KV source split).
template <int BM, int BN, int STM, bool BIAS, bool RELU, bool RES, int NBUF, bool XSWZ,
          bool ASEL, bool DUAL>
__launch_bounds__(256)
__global__ void k_gemm(const bf16* __restrict__ A, int lda, long long Az,
                       const bf16* __restrict__ Bt, int ldb, long long Bz,
                       void* __restrict__ Cv, int ldc, long long Cz,
                       int K, float alpha,
                       const float* __restrict__ bias,
                       const float* __restrict__ res,
                       const bf16* __restrict__ A2,
                       const bf16* __restrict__ Bt2,
                       void* __restrict__ Cv2,
                       const float* __restrict__ bias2,
                       const float* __restrict__ res2) {
  constexpr int FM = BM / 32, FN = BN / 32;
  constexpr int LPS = BM / 32 + BN / 32;   // global_load_lds per stage
  __shared__ __attribute__((aligned(16))) bf16 As[NBUF][BM * 64];
  __shared__ __attribute__((aligned(16))) bf16 Bs[NBUF][BN * 64];
  const int tid = threadIdx.x;
  const int w = tid >> 6, lane = tid & 63;
  int bx = blockIdx.x, by = blockIdx.y;
  if constexpr (DUAL) {
    const int half = gridDim.y >> 1;
    if (by >= half) {
      by -= half;
      A = A2; Bt = Bt2; Cv = Cv2; bias = bias2; res = res2;
    }
  }
  if constexpr (XSWZ) {
    const int nx = gridDim.x, ny = gridDim.y;
    const int lin = by * nx + bx;
    const int cpx = (nx * ny) >> 3;
    const int s = (lin & 7) * cpx + (lin >> 3);
    bx = s / ny;
    by = s - bx * ny;
  }
  const int bm = by * BM, bn = bx * BN;
  const int z = blockIdx.z;
  if constexpr (ASEL) { if (bn >= 512) A = A2; }
  A += (long long)z * Az;
  Bt += (long long)z * Bz;
  const int l15 = lane & 15, lhi = lane >> 4;
  const int wr = (w >> 1) * (BM / 2), wc = (w & 1) * (BN / 2);
  f32x4 acc[FM][FN] = {};
  const int nkt = K >> 6;  // BK = 64

  auto stage = [&](int kt, int nb) {
#pragma unroll
    for (int it = 0; it < BM / 32; ++it) {
      int chunk = (it * 4 + w) * 64 + lane;        // 16B chunks, LDS-linear dest
      int row = chunk >> 3, c = chunk & 7;
      int col = (c ^ (row & 7)) << 3;              // pre-swizzled global source
      gload_lds16(A + (size_t)(bm + row) * lda + kt * 64 + col, As[nb] + (it * 4 + w) * 512);
    }
#pragma unroll
    for (int it = 0; it < BN / 32; ++it) {
      int chunk = (it * 4 + w) * 64 + lane;
      int row = chunk >> 3, c = chunk & 7;
      int col = (c ^ (row & 7)) << 3;
      gload_lds16(Bt + (size_t)(bn + row) * ldb + kt * 64 + col, Bs[nb] + (it * 4 + w) * 512);
    }
  };
  auto waitSteady = [&]() {
    if constexpr (LPS == 3) asm volatile("s_waitcnt vmcnt(6)" ::: "memory");
    else                    asm volatile("s_waitcnt vmcnt(8)" ::: "memory");
  };
  auto compute = [&](int cb) {
#pragma unroll
    for (int kk = 0; kk < 2; ++kk) {
      short8 af[FM], bf[FN];
#pragma unroll
      for (int i = 0; i < FM; ++i) {
        int row = wr + i * 16 + l15;
        af[i] = *(const short8*)(As[cb] + row * 64 + (((kk * 4 + lhi) ^ (row & 7)) * 8));
      }
#pragma unroll
      for (int j = 0; j < FN; ++j) {
        int row = wc + j * 16 + l15;
        bf[j] = *(const short8*)(Bs[cb] + row * 64 + (((kk * 4 + lhi) ^ (row & 7)) * 8));
      }
#pragma unroll
      for (int i = 0; i < FM; ++i)
#pragma unroll
        for (int j = 0; j < FN; ++j)
          acc[i][j] = __builtin_amdgcn_mfma_f32_16x16x32_bf16(af[i], bf[j], acc[i][j], 0, 0, 0);
    }
  };

  if constexpr (NBUF == 3) {
    stage(0, 0);
    stage(1, 1);
    stage(2, 2);                                   // 3*LPS loads out
    waitSteady();                                  // tile0 landed
    __builtin_amdgcn_s_barrier();
    __builtin_amdgcn_sched_barrier(0);
    int cur = 0;
    for (int kt = 0; kt < nkt; ++kt) {
      compute(cur);
      asm volatile("s_waitcnt lgkmcnt(0)" ::: "memory");  // ds_reads of buf[cur] done
      __builtin_amdgcn_sched_barrier(0);
      if (kt + 1 < nkt) {
        __builtin_amdgcn_s_barrier();        // all waves done reading buf[cur]
        if (kt + 3 < nkt) {
          stage(kt + 3, cur);                // overwrite buf[cur]
          waitSteady();                      // stage(kt+1) landed
        } else {
          asm volatile("s_waitcnt vmcnt(0)" ::: "memory");
        }
        __builtin_amdgcn_s_barrier();        // all waves confirm next buf ready
        __builtin_amdgcn_sched_barrier(0);
      }
      cur = (cur == 2) ? 0 : cur + 1;
    }
  } else {
    for (int kt = 0; kt < nkt; ++kt) {
      stage(kt, 0);
      __syncthreads();
      compute(0);
      __syncthreads();
    }
  }

  // epilogue: C/D layout col=lane&15, row=(lane>>4)*4+r (m89-verified)
#pragma unroll
  for (int i = 0; i < FM; ++i) {
#pragma unroll
    for (int j = 0; j < FN; ++j) {
#pragma unroll
      for (int r = 0; r < 4; ++r) {
        int m = bm + wr + i * 16 + lhi * 4 + r;
        int n = bn + wc + j * 16 + l15;
        float val = acc[i][j][r] * alpha;
        if constexpr (BIAS) val += bias[n];
        if constexpr (RELU) val = fmaxf(val, 0.f);
        if constexpr (RES) val += res[(size_t)m * ldc + n];
        if constexpr (STM == ST_F32) {
          ((float*)Cv)[(size_t)z * Cz + (size_t)m * ldc + n] = val;
        } else if constexpr (STM == ST_BF16) {
          ((bf16*)Cv)[(size_t)z * Cz + (size_t)m * ldc + n] = __float2bfloat16(val);
        } else if constexpr (STM == ST_QKV) {    // n<512->Q, <1024->K (both [B,H,S,dk]), else V^T [B,H,dk,S]
          int seg = n >> 9, nn = n & 511;
          int b_ = m >> 10, s_ = m & 1023, h_ = nn >> 6, d_ = nn & 63;
          size_t idx = (seg < 2)
              ? (((size_t)(b_ * kH + h_) << 10) + s_) * kDk + d_
              : ((size_t)(b_ * kH + h_) * kDk + d_) * kS + s_;
          ((bf16*)Cv)[(size_t)seg * 1048576 + idx] = __float2bfloat16(val);
        }
      }
    }
  }
}

// ---------------- fused flash attention (unchanged from R13)
template <bool CAUSAL>
__launch_bounds__(256)
__global__ void k_fattn(const bf16* __restrict__ Q, const bf16* __restrict__ K,
                        const bf16* __restrict__ Vt, bf16* __restrict__ O) {
  __shared__ __attribute__((aligned(16))) bf16 Ks[3][4096];
  __shared__ __attribute__((aligned(16))) bf16 Vs[3][4096];
  __shared__ __attribute__((aligned(16))) bf16 Ps[4][1024];
  const int tid = threadIdx.x, w = tid >> 6, lane = tid & 63;
  const int l15 = lane & 15, lhi = lane >> 4;
  const int q0 = blockIdx.x * 64, bh = blockIdx.y;
  const int qw = q0 + w * 16;
  const bf16* Qp = Q + (((size_t)(bh << 10)) + qw + l15) * kDk;
  short8 aq[2];
  aq[0] = *(const short8*)(Qp + lhi * 8);
  aq[1] = *(const short8*)(Qp + 32 + lhi * 8);
  const int srow = w * 8 + (lane >> 3);
  const int sc = (lane & 7) ^ (srow & 7);
  const bf16* Ksrc = K + (((size_t)(bh << 10)) + srow) * kDk + sc * 8;
  const bf16* Vsrc = Vt + ((size_t)bh * kDk + srow) * kS + sc * 8;
  const int nt = CAUSAL ? (q0 >> 6) + 1 : (kS >> 6);

  auto stage = [&](int t, int nb) {
    int kv0 = t << 6;
    gload_lds16(Ksrc + (size_t)kv0 * kDk, Ks[nb] + w * 512);
    gload_lds16(Ksrc + (size_t)(kv0 + 32) * kDk, Ks[nb] + 2048 + w * 512);
    gload_lds16(Vsrc + kv0, Vs[nb] + w * 512);
    gload_lds16(Vsrc + kv0 + 32 * kS, Vs[nb] + 2048 + w * 512);
  };

  float m_[4], l_[4];
#pragma unroll
  for (int r = 0; r < 4; ++r) { m_[r] = -1e30f; l_[r] = 0.f; }
  f32x4 ao[4] = {};

  stage(0, 0);
  if (nt > 2) {
    stage(1, 1);
    stage(2, 2);
    asm volatile("s_waitcnt vmcnt(8)" ::: "memory");
  } else if (nt > 1) {
    stage(1, 1);
    asm volatile("s_waitcnt vmcnt(4)" ::: "memory");
  } else {
    asm volatile("s_waitcnt vmcnt(0)" ::: "memory");
  }
  __builtin_amdgcn_s_barrier();
  __builtin_amdgcn_sched_barrier(0);

  int cur = 0;
  for (int t = 0; t < nt; ++t) {
    f32x4 as[4] = {};
#pragma unroll
    for (int kk = 0; kk < 2; ++kk) {
      short8 bk[4];
#pragma unroll
      for (int nf = 0; nf < 4; ++nf) {
        int row = nf * 16 + l15;
        int c = (4 * kk + lhi) ^ (row & 7);
        bk[nf] = *(const short8*)(Ks[cur] + row * 64 + c * 8);
      }
#pragma unroll
      for (int nf = 0; nf < 4; ++nf)
        as[nf] = __builtin_amdgcn_mfma_f32_16x16x32_bf16(aq[kk], bk[nf], as[nf], 0, 0, 0);
    }
    float s[4][4];
#pragma unroll
    for (int nf = 0; nf < 4; ++nf)
#pragma unroll
      for (int r = 0; r < 4; ++r) {
        float v = as[nf][r] * 0.125f;
        if (CAUSAL && t == nt - 1) {
          int col = (t << 6) + nf * 16 + l15;
          int row = qw + lhi * 4 + r;
          if (col > row) v = -1e30f;
        }
        s[nf][r] = v;
      }
    float mn[4], scl[4], rsum[4];
#pragma unroll
    for (int r = 0; r < 4; ++r) {
      float mx = fmaxf(fmaxf(s[0][r], s[1][r]), fmaxf(s[2][r], s[3][r]));
      mx = fmaxf(mx, __shfl_xor(mx, 1));
      mx = fmaxf(mx, __shfl_xor(mx, 2));
      mx = fmaxf(mx, __shfl_xor(mx, 4));
      mx = fmaxf(mx, __shfl_xor(mx, 8));
      mn[r] = fmaxf(m_[r], mx);
      scl[r] = __expf(m_[r] - mn[r]);
      rsum[r] = 0.f;
    }
#pragma unroll
    for (int nf = 0; nf < 4; ++nf)
#pragma unroll
      for (int r = 0; r < 4; ++r) {
        float p = __expf(s[nf][r] - mn[r]);
        rsum[r] += p;
        int pr = lhi * 4 + r;
        int c = (2 * nf + (l15 >> 3)) ^ (pr & 7);
        Ps[w][pr * 64 + c * 8 + (l15 & 7)] = __float2bfloat16(p);
      }
#pragma unroll
    for (int r = 0; r < 4; ++r) {
      float su = rsum[r];
      su += __shfl_xor(su, 1);
      su += __shfl_xor(su, 2);
      su += __shfl_xor(su, 4);
      su += __shfl_xor(su, 8);
      l_[r] = l_[r] * scl[r] + su;
      m_[r] = mn[r];
    }
#pragma unroll
    for (int nf = 0; nf < 4; ++nf)
#pragma unroll
      for (int r = 0; r < 4; ++r) ao[nf][r] *= scl[r];
    asm volatile("s_waitcnt lgkmcnt(0)" ::: "memory");
    __builtin_amdgcn_sched_barrier(0);
#pragma unroll
    for (int kk = 0; kk < 2; ++kk) {
      short8 pa = *(const short8*)(Ps[w] + l15 * 64 + (((4 * kk + lhi) ^ (l15 & 7)) * 8));
      short8 bv[4];
#pragma unroll
      for (int nf = 0; nf < 4; ++nf) {
        int row = nf * 16 + l15;
        int c = (4 * kk + lhi) ^ (row & 7);
        bv[nf] = *(const short8*)(Vs[cur] + row * 64 + c * 8);
      }
#pragma unroll
      for (int nf = 0; nf < 4; ++nf)
        ao[nf] = __builtin_amdgcn_mfma_f32_16x16x32_bf16(pa, bv[nf], ao[nf], 0, 0, 0);
    }
    asm volatile("s_waitcnt lgkmcnt(0)" ::: "memory");
    __builtin_amdgcn_sched_barrier(0);
    if (t + 1 < nt) {
      __builtin_amdgcn_s_barrier();
      if (t + 3 < nt) {
        stage(t + 3, cur);
        asm volatile("s_waitcnt vmcnt(8)" ::: "memory");
      } else {
        asm volatile("s_waitcnt vmcnt(0)" ::: "memory");
      }
      __builtin_amdgcn_s_barrier();
      __builtin_amdgcn_sched_barrier(0);
    }
    cur = (cur == 2) ? 0 : cur + 1;
  }
  const int b_ = bh >> 3, h_ = bh & 7;
  float inv[4];
#pragma unroll
  for (int r = 0; r < 4; ++r) inv[r] = 1.f / l_[r];
#pragma unroll
  for (int nf = 0; nf < 4; ++nf)
#pragma unroll
    for (int r = 0; r < 4; ++r) {
      int q = qw + lhi * 4 + r;
      O[((size_t)(b_ * kS + q)) * kD + h_ * kDk + nf * 16 + l15] =
          __float2bfloat16(ao[nf][r] * inv[r]);
    }
}

// ---------------- prep: weight transposes + embed(+inline LN0), 1 launch (R14-verified)
struct TJobs {
  const float* src[8];
  bf16* dst[8];
  int K[8], N[8];
  int ofs[9];
};

struct PrepArgs {
  TJobs tj; int ntile;
  const int *src, *tgt;
  const float *src_emb, *tgt_emb;
  const float *eg, *eb, *dg, *db;   // first-LN params (enc l0, dec l0)
  float *x_enc, *x_dec;
  bf16 *hb_enc, *hb_dec;
};

__global__ void k_prep(PrepArgs P) {
  __shared__ float t[32][33];
  __shared__ float red[4], red2[4];
  const int tid = threadIdx.x;
  if ((int)blockIdx.x < P.ntile) {
    const int tb = blockIdx.x;
    int j = 0;
#pragma unroll
    for (int i = 1; i < 8; ++i) j += (tb >= P.tj.ofs[i]) ? 1 : 0;
    const int K = P.tj.K[j], N = P.tj.N[j];
    const int tn = N >> 5, tk = K >> 5;
    int r = tb - P.tj.ofs[j];
    const int z = r / (tn * tk);
    r -= z * tn * tk;
    const int k0 = (r / tn) << 5, n0 = (r % tn) << 5;
    const float* Wp = P.tj.src[j] + (size_t)z * K * N;
    bf16* WTp = P.tj.dst[j] + (size_t)z * K * N;
    const int tx = tid & 31, ty = tid >> 5;
#pragma unroll
    for (int rr = 0; rr < 32; rr += 8)
      t[ty + rr][tx] = Wp[(size_t)(k0 + ty + rr) * N + n0 + tx];
    __syncthreads();
#pragma unroll
    for (int rr = 0; rr < 32; rr += 8)
      WTp[(size_t)(n0 + ty + rr) * K + k0 + tx] = __float2bfloat16(t[tx][ty + rr]);
    return;
  }
  // embed + inline LN: block owns one full token row
  const int vb = blockIdx.x - P.ntile;
  const int m = vb & (kM - 1), which = vb >> 11;
  const int* tok = which ? P.tgt : P.src;
  const float* emb = which ? P.tgt_emb : P.src_emb;
  float* x = which ? P.x_dec : P.x_enc;
  const int s = m & (kS - 1);
  const float* e = emb + (size_t)tok[m] * kD;
  float* xp = x + (size_t)m * kD;
  float v[2];
#pragma unroll
  for (int h = 0; h < 2; ++h) {
    int d = tid + h * 256;
    int i = d >> 1;
    float freq = __expf(-(float)(2 * i) * (9.210340371976184f / 512.0f));
    float ang = (float)s * freq;
    float pe = (d & 1) ? cosf(ang) : sinf(ang);
    v[h] = e[d] * 22.62741699796952f + pe;
    xp[d] = v[h];
  }
  const int w = tid >> 6, lane = tid & 63;
  float sum = v[0] + v[1];
#pragma unroll
  for (int o = 32; o; o >>= 1) sum += __shfl_xor(sum, o);
  if (lane == 0) red[w] = sum;
  __syncthreads();
  sum = red[0] + red[1] + red[2] + red[3];
  const float mean = sum * (1.f / 512.f);
  float sq = (v[0] - mean) * (v[0] - mean) + (v[1] - mean) * (v[1] - mean);
#pragma unroll
  for (int o = 32; o; o >>= 1) sq += __shfl_xor(sq, o);
  if (lane == 0) red2[w] = sq;
  __syncthreads();
  sq = red2[0] + red2[1] + red2[2] + red2[3];
  const float rstd = rsqrtf(sq * (1.f / 511.f) + 1e-6f);
  const float* g = which ? P.dg : P.eg;
  const float* b = which ? P.db : P.eb;
  bf16* hb = (which ? P.hb_dec : P.hb_enc) + (size_t)m * kD;
#pragma unroll
  for (int h = 0; h < 2; ++h) {
    int d = tid + h * 256;
    hb[d] = __float2bfloat16(g[d] * (v[h] - mean) * rstd + b[d]);
  }
}

// ---------------- LayerNorm (unbiased var /511, eps 1e-6), fp32 in -> bf16 out. wave/row.
__global__ void k_ln(const float* __restrict__ x, const float* __restrict__ g,
                     const float* __restrict__ b, bf16* __restrict__ out) {
  int w = threadIdx.x >> 6, lane = threadIdx.x & 63;
  int row = blockIdx.x * 4 + w;
  const float* xp = x + (size_t)row * kD;
  float v[8];
  float sum = 0.f;
#pragma unroll
  for (int i = 0; i < 8; ++i) { v[i] = xp[lane + i * 64]; sum += v[i]; }
#pragma unroll
  for (int o = 32; o; o >>= 1) sum += __shfl_xor(sum, o);
  float mean = sum * (1.f / 512.f);
  float sq = 0.f;
#pragma unroll
  for (int i = 0; i < 8; ++i) { float d = v[i] - mean; sq += d * d; }
#pragma unroll
  for (int o = 32; o; o >>= 1) sq += __shfl_xor(sq, o);
  float inv = rsqrtf(sq * (1.f / 511.f) + 1e-6f);
  bf16* op = out + (size_t)row * kD;
#pragma unroll
  for (int i = 0; i < 8; ++i) {
    int d = lane + i * 64;
    op[d] = __float2bfloat16(g[d] * (v[i] - mean) * inv + b[d]);
  }
}

// ---------------- dual LayerNorm: grid (512, 2); y selects job (R16 launch merge)
__global__ void k_ln2(const float* __restrict__ x1, const float* __restrict__ g1,
                      const float* __restrict__ b1, bf16* __restrict__ o1,
                      const float* __restrict__ x2, const float* __restrict__ g2,
                      const float* __restrict__ b2, bf16* __restrict__ o2) {
  const int which = blockIdx.y;
  const float* x = which ? x2 : x1;
  const float* g = which ? g2 : g1;
  const float* b = which ? b2 : b1;
  bf16* out = which ? o2 : o1;
  int w = threadIdx.x >> 6, lane = threadIdx.x & 63;
  int row = blockIdx.x * 4 + w;
  const float* xp = x + (size_t)row * kD;
  float v[8];
  float sum = 0.f;
#pragma unroll
  for (int i = 0; i < 8; ++i) { v[i] = xp[lane + i * 64]; sum += v[i]; }
#pragma unroll
  for (int o = 32; o; o >>= 1) sum += __shfl_xor(sum, o);
  float mean = sum * (1.f / 512.f);
  float sq = 0.f;
#pragma unroll
  for (int i = 0; i < 8; ++i) { float d = v[i] - mean; sq += d * d; }
#pragma unroll
  for (int o = 32; o; o >>= 1) sq += __shfl_xor(sq, o);
  float inv = rsqrtf(sq * (1.f / 511.f) + 1e-6f);
  bf16* op = out + (size_t)row * kD;
#pragma unroll
  for (int i = 0; i < 8; ++i) {
    int d = lane + i * 64;
    op[d] = __float2bfloat16(g[d] * (v[i] - mean) * inv + b[d]);
  }
}

// ---------------- 256^2-tile proj GEMM (unchanged)
__global__ __launch_bounds__(512, 1) void k_proj256(const bf16* __restrict__ A,
                                                    const bf16* __restrict__ Bt,
                                                    bf16* __restrict__ C,
                                                    const float* __restrict__ bias) {
  __shared__ __attribute__((aligned(16))) bf16 As[4][256 * 32];
  __shared__ __attribute__((aligned(16))) bf16 Bs[4][256 * 32];
  const int tid = threadIdx.x, w = tid >> 6, lane = tid & 63;
  const int l15 = lane & 15, lhi = lane >> 4;
  const int lin = blockIdx.y * 125 + blockIdx.x;
  const int s = (lin & 7) * 125 + (lin >> 3);
  const int bx = s >> 3, by = s & 7;
  const int bm = by * 256, bn = bx * 256;
  const int wr = (w >> 2) * 128, wc = (w & 3) * 64;
  const int rowq = tid >> 2, chk = tid & 3;
  const int swz = (chk ^ ((rowq >> 1) & 3)) << 3;
  const bf16* Asrc0 = A + (size_t)(bm + rowq) * kD + swz;
  const bf16* Asrc1 = A + (size_t)(bm + 128 + rowq) * kD + swz;
  const bf16* Bsrc0 = Bt + (size_t)(bn + rowq) * kD + swz;
  const bf16* Bsrc1 = Bt + (size_t)(bn + 128 + rowq) * kD + swz;
  const int ldsoff = w * 1024;

  auto stage = [&](int kt) {
    const int b = kt & 3;
    const int ko = kt * 32;
    gload_lds16(Asrc0 + ko, (char*)As[b] + ldsoff);
    gload_lds16(Asrc1 + ko, (char*)As[b] + 8192 + ldsoff);
    gload_lds16(Bsrc0 + ko, (char*)Bs[b] + ldsoff);
    gload_lds16(Bsrc1 + ko, (char*)Bs[b] + 8192 + ldsoff);
  };

  const int ra = wr + l15, rb = wc + l15;
  const int abase = ra * 64 + ((lhi ^ ((ra >> 1) & 3)) << 4);
  const int bbase = rb * 64 + ((lhi ^ ((rb >> 1) & 3)) << 4);

  f32x4 acc[8][4] = {};
  stage(0); stage(1); stage(2);
  for (int kt = 0; kt < 16; ++kt) {
    if (kt + 2 < 16)      asm volatile("s_waitcnt vmcnt(8)" ::: "memory");
    else if (kt + 1 < 16) asm volatile("s_waitcnt vmcnt(4)" ::: "memory");
    else                  asm volatile("s_waitcnt vmcnt(0)" ::: "memory");
    __builtin_amdgcn_s_barrier();
    __builtin_amdgcn_sched_barrier(0);
    if (kt + 3 < 16) stage(kt + 3);
    const int b = kt & 3;
    short8 af[8], bf[4];
#pragma unroll
    for (int i = 0; i < 8; ++i)
      af[i] = *(const short8*)((const char*)As[b] + abase + i * 1024);
#pragma unroll
    for (int j = 0; j < 4; ++j)
      bf[j] = *(const short8*)((const char*)Bs[b] + bbase + j * 1024);
#pragma unroll
    for (int i = 0; i < 8; ++i)
#pragma unroll
      for (int j = 0; j < 4; ++j)
        acc[i][j] = __builtin_amdgcn_mfma_f32_16x16x32_bf16(af[i], bf[j], acc[i][j], 0, 0, 0);
    asm volatile("s_waitcnt lgkmcnt(0)" ::: "memory");
    __builtin_amdgcn_sched_barrier(0);
  }
#pragma unroll
  for (int i = 0; i < 8; ++i)
#pragma unroll
    for (int j = 0; j < 4; ++j)
#pragma unroll
      for (int r = 0; r < 4; ++r) {
        int m = bm + wr + i * 16 + lhi * 4 + r;
        int n = bn + wc + j * 16 + l15;
        C[(size_t)m * kV + n] = __float2bfloat16(acc[i][j][r] + bias[n]);
      }
}

// ---------------- log_softmax: bf16 logits -> fp32 out (unchanged)
__global__ __launch_bounds__(640, 2) void k_lsm_bf(const bf16* __restrict__ L,
                                                   float* __restrict__ y) {
  const bf16* row = L + (size_t)blockIdx.x * kV;
  float* orow = y + (size_t)blockIdx.x * kV;
  const int t = threadIdx.x;
  const bool extra = t < 160;
  float v[56];
  float sum = 0.f;
#pragma unroll
  for (int i = 0; i < 6; ++i) {
    short8 s = *(const short8*)(row + (t + i * 640) * 8);
#pragma unroll
    for (int e = 0; e < 8; ++e) {
      float f = bfu2f(s[e]);
      v[i * 8 + e] = f;
      sum += __expf(f);
    }
  }
  if (extra) {
    short8 s = *(const short8*)(row + (3840 + t) * 8);
#pragma unroll
    for (int e = 0; e < 8; ++e) {
      float f = bfu2f(s[e]);
      v[48 + e] = f;
      sum += __expf(f);
    }
  }
#pragma unroll
  for (int o = 32; o; o >>= 1) sum += __shfl_xor(sum, o);
  __shared__ float red2[10];
  const int w = t >> 6, lane = t & 63;
  if (lane == 0) red2[w] = sum;
  __syncthreads();
  sum = 0.f;
#pragma unroll
  for (int i = 0; i < 10; ++i) sum += red2[i];
  const float sh = logf(sum);
#pragma unroll
  for (int i = 0; i < 6; ++i)
#pragma unroll
    for (int e = 0; e < 8; ++e) orow[(t + i * 640) * 8 + e] = v[i * 8 + e] - sh;
  if (extra)
#pragma unroll
    for (int e = 0; e < 8; ++e) orow[(3840 + t) * 8 + e] = v[48 + e] - sh;
}

extern "C" void kernel_launch(void* const* d_in, const int* in_sizes, int n_in,
                              void* d_out, int out_size, void* d_ws, size_t ws_size,
                              hipStream_t stream) {
  (void)in_sizes; (void)n_in; (void)out_size;
  if (ws_size < (size_t)212 * 1024 * 1024) return;

  const int* src = (const int*)d_in[0];
  const int* tgt = (const int*)d_in[1];
  const float* src_emb   = (const float*)d_in[4];
  const float* tgt_emb   = (const float*)d_in[5];
  const float* enc_attn_w = (const float*)d_in[6];
  const float* enc_attn_b = (const float*)d_in[7];
  const float* enc_ffn_w1 = (const float*)d_in[8];
  const float* enc_ffn_b1 = (const float*)d_in[9];
  const float* enc_ffn_w2 = (const float*)d_in[10];
  const float* enc_ffn_b2 = (const float*)d_in[11];
  const float* enc_ln_g  = (const float*)d_in[12];
  const float* enc_ln_b  = (const float*)d_in[13];
  const float* enc_norm_g = (const float*)d_in[14];
  const float* enc_norm_b = (const float*)d_in[15];
  const float* dec_self_w = (const float*)d_in[16];
  const float* dec_self_b = (const float*)d_in[17];
  const float* dec_cross_w = (const float*)d_in[18];
  const float* dec_cross_b = (const float*)d_in[19];
  const float* dec_ffn_w1 = (const float*)d_in[20];
  const float* dec_ffn_b1 = (const float*)d_in[21];
  const float* dec_ffn_w2 = (const float*)d_in[22];
  const float* dec_ffn_b2 = (const float*)d_in[23];
  const float* dec_ln_g  = (const float*)d_in[24];
  const float* dec_ln_b  = (const float*)d_in[25];
  const float* dec_norm_g = (const float*)d_in[26];
  const float* dec_norm_b = (const float*)d_in[27];
  const float* proj_w    = (const float*)d_in[28];
  const float* proj_b    = (const float*)d_in[29];

  char* ws = (char*)d_ws;
  auto MB = [](size_t x) { return x << 20; };
  bf16* enc_attn_wt  = (bf16*)(ws + MB(0));
  bf16* dec_self_wt  = (bf16*)(ws + MB(4));
  bf16* dec_cross_wt = (bf16*)(ws + MB(8));
  bf16* enc_f1t = (bf16*)(ws + MB(12));
  bf16* enc_f2t = (bf16*)(ws + MB(16));
  bf16* dec_f1t = (bf16*)(ws + MB(20));
  bf16* dec_f2t = (bf16*)(ws + MB(24));
  bf16* proj_wt = (bf16*)(ws + MB(28));
  float* x_enc  = (float*)(ws + MB(60));
  float* x_dec  = (float*)(ws + MB(64));
  bf16* hbuf    = (bf16*)(ws + MB(68));
  bf16* enc_bf  = (bf16*)(ws + MB(70));
  bf16* Qb      = (bf16*)(ws + MB(72));  // Kb at +1Mi elems, VtB at +2Mi
  bf16* attn_o  = (bf16*)(ws + MB(78));
  bf16* logits  = (bf16*)(ws + MB(80));  // 131 MB, up to MB(211)
  bf16* hbuf2   = (bf16*)(ws + MB(208)); // dec l0 LN0/LN2 buffer (survives encoder)
  // d_out scratch: ffn_mid at +0 (8MB); dec-l0 pair buffers consumed before first ffn1
  char* dob = (char*)d_out;
  bf16* ffn_mid = (bf16*)dob;
  bf16* Qb2     = (bf16*)(dob + MB(16)); // 6 MB (Q,K,V^T segments)
  bf16* attn_o2 = (bf16*)(dob + MB(24)); // 2 MB

  // ---- prep: transposes + embed + LN0 (enc l0 LN1 -> hbuf, dec l0 LN1 -> hbuf2)
  PrepArgs P;
  int acc = 0;
  auto setj = [&](int j, const float* s, bf16* d, int K, int N, int z) {
    P.tj.src[j] = s; P.tj.dst[j] = d; P.tj.K[j] = K; P.tj.N[j] = N; P.tj.ofs[j] = acc;
    acc += (K >> 5) * (N >> 5) * z;
  };
  setj(0, enc_attn_w, enc_attn_wt, 512, 512, 8);
  setj(1, dec_self_w, dec_self_wt, 512, 512, 8);
  setj(2, dec_cross_w, dec_cross_wt, 512, 512, 8);
  setj(3, enc_ffn_w1, enc_f1t, 512, 2048, 2);
  setj(4, enc_ffn_w2, enc_f2t, 2048, 512, 2);
  setj(5, dec_ffn_w1, dec_f1t, 512, 2048, 2);
  setj(6, dec_ffn_w2, dec_f2t, 2048, 512, 2);
  setj(7, proj_w, proj_wt, 512, 32000, 1);
  P.tj.ofs[8] = acc;
  P.ntile = acc;
  P.src = src; P.tgt = tgt;
  P.src_emb = src_emb; P.tgt_emb = tgt_emb;
  P.eg = enc_ln_g; P.eb = enc_ln_b;
  P.dg = dec_ln_g; P.db = dec_ln_b;
  P.x_enc = x_enc; P.x_dec = x_dec;
  P.hb_enc = hbuf; P.hb_dec = hbuf2;
  k_prep<<<acc + 2 * kM, 256, 0, stream>>>(P);

  // ---- helpers (single-job versions; N/A slots nullptr)
  auto qkv = [&](const bf16* aptr, const bf16* wt, const float* bias, const bf16* kvA) {
    if (kvA)
      k_gemm<64, 64, ST_QKV, true, false, false, 3, false, true, false>
          <<<dim3(24, 32, 1), 256, 0, stream>>>(
          aptr, 512, 0, wt, 512, 0, Qb, 0, 0, 512, 1.f, bias, nullptr, kvA,
          nullptr, nullptr, nullptr, nullptr);
    else
      k_gemm<64, 64, ST_QKV, true, false, false, 3, false, false, false>
          <<<dim3(24, 32, 1), 256, 0, stream>>>(
          aptr, 512, 0, wt, 512, 0, Qb, 0, 0, 512, 1.f, bias, nullptr, nullptr,
          nullptr, nullptr, nullptr, nullptr);
  };
  auto fattn = [&](bool causal, const bf16* qb, bf16* ao) {
    if (causal) k_fattn<true><<<dim3(16, kBH), 256, 0, stream>>>(qb, qb + 1048576, qb + 2097152, ao);
    else        k_fattn<false><<<dim3(16, kBH), 256, 0, stream>>>(qb, qb + 1048576, qb + 2097152, ao);
  };
  auto out_proj = [&](const bf16* ao, const bf16* wt, const float* bias, float* xio) {
    k_gemm<32, 64, ST_F32, true, false, true, 3, false, false, false>
        <<<dim3(8, 64, 1), 256, 0, stream>>>(
        ao, 512, 0, wt + 3 * 262144, 512, 0, xio, 512, 0, 512, 1.f, bias + 3 * 512,
        xio, nullptr, nullptr, nullptr, nullptr, nullptr);
  };
  auto LN = [&](const float* x, const float* g, const float* b, bf16* out) {
    k_ln<<<kM / 4, 256, 0, stream>>>(x, g, b, out);
  };
  auto ffn = [&](float* xio, const bf16* w1t, const float* b1, const bf16* w2t,
                 const float* b2) {
    k_gemm<64, 64, ST_BF16, true, true, false, 3, false, false, false>
        <<<dim3(32, 32, 1), 256, 0, stream>>>(
        hbuf, 512, 0, w1t, 512, 0, ffn_mid, kF, 0, 512, 1.f, b1, nullptr, nullptr,
        nullptr, nullptr, nullptr, nullptr);
    k_gemm<32, 64, ST_F32, true, false, true, 3, false, false, false>
        <<<dim3(8, 64, 1), 256, 0, stream>>>(
        ffn_mid, 2048, 0, w2t, 2048, 0, xio, 512, 0, 2048, 1.f, b2, xio, nullptr,
        nullptr, nullptr, nullptr, nullptr);
  };

  // ---- PAIRED phase: enc-l0 {QKV, fattn, outproj, LN2} || dec-l0 self {same}
  // QKV pair: grid (24, 64); upper half = dec job (hbuf2 -> Qb2)
  k_gemm<64, 64, ST_QKV, true, false, false, 3, false, false, true>
      <<<dim3(24, 64, 1), 256, 0, stream>>>(
      hbuf, 512, 0, enc_attn_wt, 512, 0, Qb, 0, 0, 512, 1.f, enc_attn_b, nullptr,
      hbuf2, dec_self_wt, Qb2, dec_self_b, nullptr);
  fattn(false, Qb, attn_o);
  fattn(true, Qb2, attn_o2);
  // outproj pair: grid (8, 128); upper half = dec job
  k_gemm<32, 64, ST_F32, true, false, true, 3, false, false, true>
      <<<dim3(8, 128, 1), 256, 0, stream>>>(
      attn_o, 512, 0, enc_attn_wt + 3 * 262144, 512, 0, x_enc, 512, 0, 512, 1.f,
      enc_attn_b + 3 * 512, x_enc,
      attn_o2, dec_self_wt + 3 * 262144, x_dec, dec_self_b + 3 * 512, x_dec);
  // LN pair: enc LN2 -> hbuf, dec LN2 -> hbuf2
  k_ln2<<<dim3(kM / 4, 2), 256, 0, stream>>>(
      x_enc, enc_ln_g + 512, enc_ln_b + 512, hbuf,
      x_dec, dec_ln_g + 512, dec_ln_b + 512, hbuf2);

  // ---- encoder remainder
  ffn(x_enc, enc_f1t, enc_ffn_b1, enc_f2t, enc_ffn_b2);                 // layer 0 FFN
  LN(x_enc, enc_ln_g + 1024, enc_ln_b + 1024, hbuf);                    // l1 LN1
  qkv(hbuf, enc_attn_wt + 1048576, enc_attn_b + 2048, nullptr);
  fattn(false, Qb, attn_o);
  out_proj(attn_o, enc_attn_wt + 1048576, enc_attn_b + 2048, x_enc);
  LN(x_enc, enc_ln_g + 1024 + 512, enc_ln_b + 1024 + 512, hbuf);        // l1 LN2
  ffn(x_enc, enc_f1t + 1048576, enc_ffn_b1 + 2048, enc_f2t + 1048576, enc_ffn_b2 + 512);
  LN(x_enc, enc_norm_g, enc_norm_b, enc_bf);                            // final LN

  // ---- decoder (l0 resumes at cross-attn; hbuf2 holds LN2(x_dec))
  for (int i = 0; i < 2; ++i) {
    const bf16* wts = dec_self_wt + (size_t)i * 1048576;
    const float* bs = dec_self_b + i * 2048;
    const bf16* wtc = dec_cross_wt + (size_t)i * 1048576;
    const float* bc = dec_cross_b + i * 2048;
    if (i == 1) {
      LN(x_dec, dec_ln_g + 1536, dec_ln_b + 1536, hbuf);                // l1 LN1
      qkv(hbuf, wts, bs, nullptr);
      fattn(true, Qb, attn_o);
      out_proj(attn_o, wts, bs, x_dec);
      LN(x_dec, dec_ln_g + 1536 + 512, dec_ln_b + 1536 + 512, hbuf);    // l1 LN2
    }
    const bf16* qsrc = (i == 0) ? hbuf2 : hbuf;
    qkv(qsrc, wtc, bc, enc_bf);                                         // cross QKV
    fattn(false, Qb, attn_o);
    out_proj(attn_o, wtc, bc, x_dec);
    LN(x_dec, dec_ln_g + i * 1536 + 1024, dec_ln_b + i * 1536 + 1024, hbuf);  // LN3
    ffn(x_dec, dec_f1t + (size_t)i * 1048576, dec_ffn_b1 + i * 2048,
        dec_f2t + (size_t)i * 1048576, dec_ffn_b2 + i * 512);
  }
  LN(x_dec, dec_norm_g, dec_norm_b, hbuf);                              // final LN

  // logits -> log_softmax
  k_proj256<<<dim3(125, 8), 512, 0, stream>>>(hbuf, proj_wt, logits, proj_b);
  k_lsm_bf<<<kM, 640, 0, stream>>>(logits, (float*)d_out);
}

// Round 17
// 645.198 us; speedup vs baseline: 1.5977x; 1.0266x over previous
//
#include <hip/hip_runtime.h>
#include <hip/hip_bf16.h>
#include <math.h>

using bf16 = __hip_bfloat16;
typedef float f32x4 __attribute__((ext_vector_type(4)));
typedef short short8 __attribute__((ext_vector_type(8)));

constexpr int kD = 512, kH = 8, kDk = 64, kF = 2048, kV = 32000;
constexpr int kB = 2, kS = 1024, kM = 2048, kBH = 16;  // kM = B*S tokens

enum { ST_F32 = 0, ST_BF16, ST_QKV };

__device__ __forceinline__ void gload_lds16(const void* g, void* l) {
  __builtin_amdgcn_global_load_lds(
      (const __attribute__((address_space(1))) void*)g,
      (__attribute__((address_space(3))) void*)l, 16, 0, 0);
}

__device__ __forceinline__ float bfu2f(short u) {
  union { unsigned int i; float f; } c;
  c.i = ((unsigned int)(unsigned short)u) << 16;
  return c.f;
}

// ---------------- generic MFMA GEMM: C = A[M,K] @ Bt[N,K]^T (+bias)(+relu)(+res)
// BMxBN tiles, 4 waves (2x2), 3-deep counted-vmcnt pipeline, XOR-swizzled LDS (R13).
// DUAL: grid.y doubled; upper half switches {A,Bt,Cv,bias,res} to job 2.
// ASEL: blocks with bn>=512 read A2 (cross-attn Q/KV source split).
template <int BM, int BN, int STM, bool BIAS, bool RELU, bool RES, int NBUF, bool XSWZ,
          bool ASEL, bool DUAL>
__launch_bounds__(256)
__global__ void k_gemm(const bf16* __restrict__ A, int lda, long long Az,
                       const bf16* __restrict__ Bt, int ldb, long long Bz,
                       void* __restrict__ Cv, int ldc, long long Cz,
                       int K, float alpha,
                       const float* __restrict__ bias,
                       const float* __restrict__ res,
                       const bf16* __restrict__ A2,
                       const bf16* __restrict__ Bt2,
                       void* __restrict__ Cv2,
                       const float* __restrict__ bias2,
                       const float* __restrict__ res2) {
  constexpr int FM = BM / 32, FN = BN / 32;
  constexpr int LPS = BM / 32 + BN / 32;   // global_load_lds per stage
  __shared__ __attribute__((aligned(16))) bf16 As[NBUF][BM * 64];
  __shared__ __attribute__((aligned(16))) bf16 Bs[NBUF][BN * 64];
  const int tid = threadIdx.x;
  const int w = tid >> 6, lane = tid & 63;
  int bx = blockIdx.x, by = blockIdx.y;
  if constexpr (DUAL) {
    const int half = gridDim.y >> 1;
    if (by >= half) {
      by -= half;
      A = A2; Bt = Bt2; Cv = Cv2; bias = bias2; res = res2;
    }
  }
  if constexpr (XSWZ) {
    const int nx = gridDim.x, ny = gridDim.y;
    const int lin = by * nx + bx;
    const int cpx = (nx * ny) >> 3;
    const int s = (lin & 7) * cpx + (lin >> 3);
    bx = s / ny;
    by = s - bx * ny;
  }
  const int bm = by * BM, bn = bx * BN;
  const int z = blockIdx.z;
  if constexpr (ASEL) { if (bn >= 512) A = A2; }
  A += (long long)z * Az;
  Bt += (long long)z * Bz;
  const int l15 = lane & 15, lhi = lane >> 4;
  const int wr = (w >> 1) * (BM / 2), wc = (w & 1) * (BN / 2);
  f32x4 acc[FM][FN] = {};
  const int nkt = K >> 6;  // BK = 64

  auto stage = [&](int kt, int nb) {
#pragma unroll
    for (int it = 0; it < BM / 32; ++it) {
      int chunk = (it * 4 + w) * 64 + lane;        // 16B chunks, LDS-linear dest
      int row = chunk >> 3, c = chunk & 7;
      int col = (c ^ (row & 7)) << 3;              // pre-swizzled global source
      gload_lds16(A + (size_t)(bm + row) * lda + kt * 64 + col, As[nb] + (it * 4 + w) * 512);
    }
#pragma unroll
    for (int it = 0; it < BN / 32; ++it) {
      int chunk = (it * 4 + w) * 64 + lane;
      int row = chunk >> 3, c = chunk & 7;
      int col = (c ^ (row & 7)) << 3;
      gload_lds16(Bt + (size_t)(bn + row) * ldb + kt * 64 + col, Bs[nb] + (it * 4 + w) * 512);
    }
  };
  auto waitSteady = [&]() {
    if constexpr (LPS == 3) asm volatile("s_waitcnt vmcnt(6)" ::: "memory");
    else                    asm volatile("s_waitcnt vmcnt(8)" ::: "memory");
  };
  auto compute = [&](int cb) {
#pragma unroll
    for (int kk = 0; kk < 2; ++kk) {
      short8 af[FM], bf[FN];
#pragma unroll
      for (int i = 0; i < FM; ++i) {
        int row = wr + i * 16 + l15;
        af[i] = *(const short8*)(As[cb] + row * 64 + (((kk * 4 + lhi) ^ (row & 7)) * 8));
      }
#pragma unroll
      for (int j = 0; j < FN; ++j) {
        int row = wc + j * 16 + l15;
        bf[j] = *(const short8*)(Bs[cb] + row * 64 + (((kk * 4 + lhi) ^ (row & 7)) * 8));
      }
#pragma unroll
      for (int i = 0; i < FM; ++i)
#pragma unroll
        for (int j = 0; j < FN; ++j)
          acc[i][j] = __builtin_amdgcn_mfma_f32_16x16x32_bf16(af[i], bf[j], acc[i][j], 0, 0, 0);
    }
  };

  if constexpr (NBUF == 3) {
    stage(0, 0);
    stage(1, 1);
    stage(2, 2);                                   // 3*LPS loads out
    waitSteady();                                  // tile0 landed
    __builtin_amdgcn_s_barrier();
    __builtin_amdgcn_sched_barrier(0);
    int cur = 0;
    for (int kt = 0; kt < nkt; ++kt) {
      compute(cur);
      asm volatile("s_waitcnt lgkmcnt(0)" ::: "memory");  // ds_reads of buf[cur] done
      __builtin_amdgcn_sched_barrier(0);
      if (kt + 1 < nkt) {
        __builtin_amdgcn_s_barrier();        // all waves done reading buf[cur]
        if (kt + 3 < nkt) {
          stage(kt + 3, cur);                // overwrite buf[cur]
          waitSteady();                      // stage(kt+1) landed
        } else {
          asm volatile("s_waitcnt vmcnt(0)" ::: "memory");
        }
        __builtin_amdgcn_s_barrier();        // all waves confirm next buf ready
        __builtin_amdgcn_sched_barrier(0);
      }
      cur = (cur == 2) ? 0 : cur + 1;
    }
  } else {
    for (int kt = 0; kt < nkt; ++kt) {
      stage(kt, 0);
      __syncthreads();
      compute(0);
      __syncthreads();
    }
  }

  // epilogue: C/D layout col=lane&15, row=(lane>>4)*4+r (m89-verified)
#pragma unroll
  for (int i = 0; i < FM; ++i) {
#pragma unroll
    for (int j = 0; j < FN; ++j) {
#pragma unroll
      for (int r = 0; r < 4; ++r) {
        int m = bm + wr + i * 16 + lhi * 4 + r;
        int n = bn + wc + j * 16 + l15;
        float val = acc[i][j][r] * alpha;
        if constexpr (BIAS) val += bias[n];
        if constexpr (RELU) val = fmaxf(val, 0.f);
        if constexpr (RES) val += res[(size_t)m * ldc + n];
        if constexpr (STM == ST_F32) {
          ((float*)Cv)[(size_t)z * Cz + (size_t)m * ldc + n] = val;
        } else if constexpr (STM == ST_BF16) {
          ((bf16*)Cv)[(size_t)z * Cz + (size_t)m * ldc + n] = __float2bfloat16(val);
        } else if constexpr (STM == ST_QKV) {    // n<512->Q, <1024->K (both [B,H,S,dk]), else V^T [B,H,dk,S]
          int seg = n >> 9, nn = n & 511;
          int b_ = m >> 10, s_ = m & 1023, h_ = nn >> 6, d_ = nn & 63;
          size_t idx = (seg < 2)
              ? (((size_t)(b_ * kH + h_) << 10) + s_) * kDk + d_
              : ((size_t)(b_ * kH + h_) * kDk + d_) * kS + s_;
          ((bf16*)Cv)[(size_t)seg * 1048576 + idx] = __float2bfloat16(val);
        }
      }
    }
  }
}

// ---------------- fused flash attention core (R13 body + T5 setprio around MFMA).
// DUAL2: runtime causal flag + per-job Q/O; grid.y doubled when used.
__device__ __forceinline__ void fattn_body(const bf16* __restrict__ Q,
                                           const bf16* __restrict__ K,
                                           const bf16* __restrict__ Vt,
                                           bf16* __restrict__ O,
                                           int q0, int bh, bool causal,
                                           bf16 (*Ks)[4096], bf16 (*Vs)[4096],
                                           bf16 (*Ps)[1024]) {
  const int tid = threadIdx.x, w = tid >> 6, lane = tid & 63;
  const int l15 = lane & 15, lhi = lane >> 4;
  const int qw = q0 + w * 16;
  const bf16* Qp = Q + (((size_t)(bh << 10)) + qw + l15) * kDk;
  short8 aq[2];
  aq[0] = *(const short8*)(Qp + lhi * 8);
  aq[1] = *(const short8*)(Qp + 32 + lhi * 8);
  const int srow = w * 8 + (lane >> 3);
  const int sc = (lane & 7) ^ (srow & 7);
  const bf16* Ksrc = K + (((size_t)(bh << 10)) + srow) * kDk + sc * 8;
  const bf16* Vsrc = Vt + ((size_t)bh * kDk + srow) * kS + sc * 8;
  const int nt = causal ? (q0 >> 6) + 1 : (kS >> 6);

  auto stage = [&](int t, int nb) {
    int kv0 = t << 6;
    gload_lds16(Ksrc + (size_t)kv0 * kDk, Ks[nb] + w * 512);
    gload_lds16(Ksrc + (size_t)(kv0 + 32) * kDk, Ks[nb] + 2048 + w * 512);
    gload_lds16(Vsrc + kv0, Vs[nb] + w * 512);
    gload_lds16(Vsrc + kv0 + 32 * kS, Vs[nb] + 2048 + w * 512);
  };

  float m_[4], l_[4];
#pragma unroll
  for (int r = 0; r < 4; ++r) { m_[r] = -1e30f; l_[r] = 0.f; }
  f32x4 ao[4] = {};

  stage(0, 0);
  if (nt > 2) {
    stage(1, 1);
    stage(2, 2);
    asm volatile("s_waitcnt vmcnt(8)" ::: "memory");
  } else if (nt > 1) {
    stage(1, 1);
    asm volatile("s_waitcnt vmcnt(4)" ::: "memory");
  } else {
    asm volatile("s_waitcnt vmcnt(0)" ::: "memory");
  }
  __builtin_amdgcn_s_barrier();
  __builtin_amdgcn_sched_barrier(0);

  int cur = 0;
  for (int t = 0; t < nt; ++t) {
    f32x4 as[4] = {};
    __builtin_amdgcn_s_setprio(1);
#pragma unroll
    for (int kk = 0; kk < 2; ++kk) {
      short8 bk[4];
#pragma unroll
      for (int nf = 0; nf < 4; ++nf) {
        int row = nf * 16 + l15;
        int c = (4 * kk + lhi) ^ (row & 7);
        bk[nf] = *(const short8*)(Ks[cur] + row * 64 + c * 8);
      }
#pragma unroll
      for (int nf = 0; nf < 4; ++nf)
        as[nf] = __builtin_amdgcn_mfma_f32_16x16x32_bf16(aq[kk], bk[nf], as[nf], 0, 0, 0);
    }
    __builtin_amdgcn_s_setprio(0);
    float s[4][4];
#pragma unroll
    for (int nf = 0; nf < 4; ++nf)
#pragma unroll
      for (int r = 0; r < 4; ++r) {
        float v = as[nf][r] * 0.125f;
        if (causal && t == nt - 1) {
          int col = (t << 6) + nf * 16 + l15;
          int row = qw + lhi * 4 + r;
          if (col > row) v = -1e30f;
        }
        s[nf][r] = v;
      }
    float mn[4], scl[4], rsum[4];
#pragma unroll
    for (int r = 0; r < 4; ++r) {
      float mx = fmaxf(fmaxf(s[0][r], s[1][r]), fmaxf(s[2][r], s[3][r]));
      mx = fmaxf(mx, __shfl_xor(mx, 1));
      mx = fmaxf(mx, __shfl_xor(mx, 2));
      mx = fmaxf(mx, __shfl_xor(mx, 4));
      mx = fmaxf(mx, __shfl_xor(mx, 8));
      mn[r] = fmaxf(m_[r], mx);
      scl[r] = __expf(m_[r] - mn[r]);
      rsum[r] = 0.f;
    }
#pragma unroll
    for (int nf = 0; nf < 4; ++nf)
#pragma unroll
      for (int r = 0; r < 4; ++r) {
        float p = __expf(s[nf][r] - mn[r]);
        rsum[r] += p;
        int pr = lhi * 4 + r;
        int c = (2 * nf + (l15 >> 3)) ^ (pr & 7);
        Ps[w][pr * 64 + c * 8 + (l15 & 7)] = __float2bfloat16(p);
      }
#pragma unroll
    for (int r = 0; r < 4; ++r) {
      float su = rsum[r];
      su += __shfl_xor(su, 1);
      su += __shfl_xor(su, 2);
      su += __shfl_xor(su, 4);
      su += __shfl_xor(su, 8);
      l_[r] = l_[r] * scl[r] + su;
      m_[r] = mn[r];
    }
#pragma unroll
    for (int nf = 0; nf < 4; ++nf)
#pragma unroll
      for (int r = 0; r < 4; ++r) ao[nf][r] *= scl[r];
    asm volatile("s_waitcnt lgkmcnt(0)" ::: "memory");
    __builtin_amdgcn_sched_barrier(0);
    __builtin_amdgcn_s_setprio(1);
#pragma unroll
    for (int kk = 0; kk < 2; ++kk) {
      short8 pa = *(const short8*)(Ps[w] + l15 * 64 + (((4 * kk + lhi) ^ (l15 & 7)) * 8));
      short8 bv[4];
#pragma unroll
      for (int nf = 0; nf < 4; ++nf) {
        int row = nf * 16 + l15;
        int c = (4 * kk + lhi) ^ (row & 7);
        bv[nf] = *(const short8*)(Vs[cur] + row * 64 + c * 8);
      }
#pragma unroll
      for (int nf = 0; nf < 4; ++nf)
        ao[nf] = __builtin_amdgcn_mfma_f32_16x16x32_bf16(pa, bv[nf], ao[nf], 0, 0, 0);
    }
    __builtin_amdgcn_s_setprio(0);
    asm volatile("s_waitcnt lgkmcnt(0)" ::: "memory");
    __builtin_amdgcn_sched_barrier(0);
    if (t + 1 < nt) {
      __builtin_amdgcn_s_barrier();
      if (t + 3 < nt) {
        stage(t + 3, cur);
        asm volatile("s_waitcnt vmcnt(8)" ::: "memory");
      } else {
        asm volatile("s_waitcnt vmcnt(0)" ::: "memory");
      }
      __builtin_amdgcn_s_barrier();
      __builtin_amdgcn_sched_barrier(0);
    }
    cur = (cur == 2) ? 0 : cur + 1;
  }
  const int b_ = bh >> 3, h_ = bh & 7;
  float inv[4];
#pragma unroll
  for (int r = 0; r < 4; ++r) inv[r] = 1.f / l_[r];
#pragma unroll
  for (int nf = 0; nf < 4; ++nf)
#pragma unroll
    for (int r = 0; r < 4; ++r) {
      int q = qw + lhi * 4 + r;
      O[((size_t)(b_ * kS + q)) * kD + h_ * kDk + nf * 16 + l15] =
          __float2bfloat16(ao[nf][r] * inv[r]);
    }
}

template <bool CAUSAL>
__launch_bounds__(256)
__global__ void k_fattn(const bf16* __restrict__ Q, const bf16* __restrict__ K,
                        const bf16* __restrict__ Vt, bf16* __restrict__ O) {
  __shared__ __attribute__((aligned(16))) bf16 Ks[3][4096];
  __shared__ __attribute__((aligned(16))) bf16 Vs[3][4096];
  __shared__ __attribute__((aligned(16))) bf16 Ps[4][1024];
  fattn_body(Q, K, Vt, O, blockIdx.x * 64, blockIdx.y, CAUSAL, Ks, Vs, Ps);
}

// dual-job flash attention: grid (16, 2*kBH); upper half = job 2 (own Q/K/V/O + causal2)
__launch_bounds__(256)
__global__ void k_fattn2(const bf16* __restrict__ Q1, bf16* __restrict__ O1, int c1,
                         const bf16* __restrict__ Q2, bf16* __restrict__ O2, int c2) {
  __shared__ __attribute__((aligned(16))) bf16 Ks[3][4096];
  __shared__ __attribute__((aligned(16))) bf16 Vs[3][4096];
  __shared__ __attribute__((aligned(16))) bf16 Ps[4][1024];
  int by = blockIdx.y;
  const bf16* Q = Q1; bf16* O = O1; bool causal = c1;
  if (by >= kBH) { by -= kBH; Q = Q2; O = O2; causal = c2; }
  fattn_body(Q, Q + 1048576, Q + 2097152, O, blockIdx.x * 64, by, causal, Ks, Vs, Ps);
}

// ---------------- prep: weight transposes + embed(+inline LN0), 1 launch (R14-verified)
struct TJobs {
  const float* src[8];
  bf16* dst[8];
  int K[8], N[8];
  int ofs[9];
};

struct PrepArgs {
  TJobs tj; int ntile;
  const int *src, *tgt;
  const float *src_emb, *tgt_emb;
  const float *eg, *eb, *dg, *db;   // first-LN params (enc l0, dec l0)
  float *x_enc, *x_dec;
  bf16 *hb_enc, *hb_dec;
};

__global__ void k_prep(PrepArgs P) {
  __shared__ float t[32][33];
  __shared__ float red[4], red2[4];
  const int tid = threadIdx.x;
  if ((int)blockIdx.x < P.ntile) {
    const int tb = blockIdx.x;
    int j = 0;
#pragma unroll
    for (int i = 1; i < 8; ++i) j += (tb >= P.tj.ofs[i]) ? 1 : 0;
    const int K = P.tj.K[j], N = P.tj.N[j];
    const int tn = N >> 5, tk = K >> 5;
    int r = tb - P.tj.ofs[j];
    const int z = r / (tn * tk);
    r -= z * tn * tk;
    const int k0 = (r / tn) << 5, n0 = (r % tn) << 5;
    const float* Wp = P.tj.src[j] + (size_t)z * K * N;
    bf16* WTp = P.tj.dst[j] + (size_t)z * K * N;
    const int tx = tid & 31, ty = tid >> 5;
#pragma unroll
    for (int rr = 0; rr < 32; rr += 8)
      t[ty + rr][tx] = Wp[(size_t)(k0 + ty + rr) * N + n0 + tx];
    __syncthreads();
#pragma unroll
    for (int rr = 0; rr < 32; rr += 8)
      WTp[(size_t)(n0 + ty + rr) * K + k0 + tx] = __float2bfloat16(t[tx][ty + rr]);
    return;
  }
  // embed + inline LN: block owns one full token row
  const int vb = blockIdx.x - P.ntile;
  const int m = vb & (kM - 1), which = vb >> 11;
  const int* tok = which ? P.tgt : P.src;
  const float* emb = which ? P.tgt_emb : P.src_emb;
  float* x = which ? P.x_dec : P.x_enc;
  const int s = m & (kS - 1);
  const float* e = emb + (size_t)tok[m] * kD;
  float* xp = x + (size_t)m * kD;
  float v[2];
#pragma unroll
  for (int h = 0; h < 2; ++h) {
    int d = tid + h * 256;
    int i = d >> 1;
    float freq = __expf(-(float)(2 * i) * (9.210340371976184f / 512.0f));
    float ang = (float)s * freq;
    float pe = (d & 1) ? cosf(ang) : sinf(ang);
    v[h] = e[d] * 22.62741699796952f + pe;
    xp[d] = v[h];
  }
  const int w = tid >> 6, lane = tid & 63;
  float sum = v[0] + v[1];
#pragma unroll
  for (int o = 32; o; o >>= 1) sum += __shfl_xor(sum, o);
  if (lane == 0) red[w] = sum;
  __syncthreads();
  sum = red[0] + red[1] + red[2] + red[3];
  const float mean = sum * (1.f / 512.f);
  float sq = (v[0] - mean) * (v[0] - mean) + (v[1] - mean) * (v[1] - mean);
#pragma unroll
  for (int o = 32; o; o >>= 1) sq += __shfl_xor(sq, o);
  if (lane == 0) red2[w] = sq;
  __syncthreads();
  sq = red2[0] + red2[1] + red2[2] + red2[3];
  const float rstd = rsqrtf(sq * (1.f / 511.f) + 1e-6f);
  const float* g = which ? P.dg : P.eg;
  const float* b = which ? P.db : P.eb;
  bf16* hb = (which ? P.hb_dec : P.hb_enc) + (size_t)m * kD;
#pragma unroll
  for (int h = 0; h < 2; ++h) {
    int d = tid + h * 256;
    hb[d] = __float2bfloat16(g[d] * (v[h] - mean) * rstd + b[d]);
  }
}

// ---------------- LayerNorm (unbiased var /511, eps 1e-6), fp32 in -> bf16 out. wave/row.
__global__ void k_ln(const float* __restrict__ x, const float* __restrict__ g,
                     const float* __restrict__ b, bf16* __restrict__ out) {
  int w = threadIdx.x >> 6, lane = threadIdx.x & 63;
  int row = blockIdx.x * 4 + w;
  const float* xp = x + (size_t)row * kD;
  float v[8];
  float sum = 0.f;
#pragma unroll
  for (int i = 0; i < 8; ++i) { v[i] = xp[lane + i * 64]; sum += v[i]; }
#pragma unroll
  for (int o = 32; o; o >>= 1) sum += __shfl_xor(sum, o);
  float mean = sum * (1.f / 512.f);
  float sq = 0.f;
#pragma unroll
  for (int i = 0; i < 8; ++i) { float d = v[i] - mean; sq += d * d; }
#pragma unroll
  for (int o = 32; o; o >>= 1) sq += __shfl_xor(sq, o);
  float inv = rsqrtf(sq * (1.f / 511.f) + 1e-6f);
  bf16* op = out + (size_t)row * kD;
#pragma unroll
  for (int i = 0; i < 8; ++i) {
    int d = lane + i * 64;
    op[d] = __float2bfloat16(g[d] * (v[i] - mean) * inv + b[d]);
  }
}

// ---------------- dual LayerNorm: grid (512, 2); y selects job
__global__ void k_ln2(const float* __restrict__ x1, const float* __restrict__ g1,
                      const float* __restrict__ b1, bf16* __restrict__ o1,
                      const float* __restrict__ x2, const float* __restrict__ g2,
                      const float* __restrict__ b2, bf16* __restrict__ o2) {
  const int which = blockIdx.y;
  const float* x = which ? x2 : x1;
  const float* g = which ? g2 : g1;
  const float* b = which ? b2 : b1;
  bf16* out = which ? o2 : o1;
  int w = threadIdx.x >> 6, lane = threadIdx.x & 63;
  int row = blockIdx.x * 4 + w;
  const float* xp = x + (size_t)row * kD;
  float v[8];
  float sum = 0.f;
#pragma unroll
  for (int i = 0; i < 8; ++i) { v[i] = xp[lane + i * 64]; sum += v[i]; }
#pragma unroll
  for (int o = 32; o; o >>= 1) sum += __shfl_xor(sum, o);
  float mean = sum * (1.f / 512.f);
  float sq = 0.f;
#pragma unroll
  for (int i = 0; i < 8; ++i) { float d = v[i] - mean; sq += d * d; }
#pragma unroll
  for (int o = 32; o; o >>= 1) sq += __shfl_xor(sq, o);
  float inv = rsqrtf(sq * (1.f / 511.f) + 1e-6f);
  bf16* op = out + (size_t)row * kD;
#pragma unroll
  for (int i = 0; i < 8; ++i) {
    int d = lane + i * 64;
    op[d] = __float2bfloat16(g[d] * (v[i] - mean) * inv + b[d]);
  }
}

// ---------------- 256^2-tile proj GEMM (+T5 setprio around MFMA cluster)
__global__ __launch_bounds__(512, 1) void k_proj256(const bf16* __restrict__ A,
                                                    const bf16* __restrict__ Bt,
                                                    bf16* __restrict__ C,
                                                    const float* __restrict__ bias) {
  __shared__ __attribute__((aligned(16))) bf16 As[4][256 * 32];
  __shared__ __attribute__((aligned(16))) bf16 Bs[4][256 * 32];
  const int tid = threadIdx.x, w = tid >> 6, lane = tid & 63;
  const int l15 = lane & 15, lhi = lane >> 4;
  const int lin = blockIdx.y * 125 + blockIdx.x;
  const int s = (lin & 7) * 125 + (lin >> 3);
  const int bx = s >> 3, by = s & 7;
  const int bm = by * 256, bn = bx * 256;
  const int wr = (w >> 2) * 128, wc = (w & 3) * 64;
  const int rowq = tid >> 2, chk = tid & 3;
  const int swz = (chk ^ ((rowq >> 1) & 3)) << 3;
  const bf16* Asrc0 = A + (size_t)(bm + rowq) * kD + swz;
  const bf16* Asrc1 = A + (size_t)(bm + 128 + rowq) * kD + swz;
  const bf16* Bsrc0 = Bt + (size_t)(bn + rowq) * kD + swz;
  const bf16* Bsrc1 = Bt + (size_t)(bn + 128 + rowq) * kD + swz;
  const int ldsoff = w * 1024;

  auto stage = [&](int kt) {
    const int b = kt & 3;
    const int ko = kt * 32;
    gload_lds16(Asrc0 + ko, (char*)As[b] + ldsoff);
    gload_lds16(Asrc1 + ko, (char*)As[b] + 8192 + ldsoff);
    gload_lds16(Bsrc0 + ko, (char*)Bs[b] + ldsoff);
    gload_lds16(Bsrc1 + ko, (char*)Bs[b] + 8192 + ldsoff);
  };

  const int ra = wr + l15, rb = wc + l15;
  const int abase = ra * 64 + ((lhi ^ ((ra >> 1) & 3)) << 4);
  const int bbase = rb * 64 + ((lhi ^ ((rb >> 1) & 3)) << 4);

  f32x4 acc[8][4] = {};
  stage(0); stage(1); stage(2);
  for (int kt = 0; kt < 16; ++kt) {
    if (kt + 2 < 16)      asm volatile("s_waitcnt vmcnt(8)" ::: "memory");
    else if (kt + 1 < 16) asm volatile("s_waitcnt vmcnt(4)" ::: "memory");
    else                  asm volatile("s_waitcnt vmcnt(0)" ::: "memory");
    __builtin_amdgcn_s_barrier();
    __builtin_amdgcn_sched_barrier(0);
    if (kt + 3 < 16) stage(kt + 3);
    const int b = kt & 3;
    short8 af[8], bf[4];
#pragma unroll
    for (int i = 0; i < 8; ++i)
      af[i] = *(const short8*)((const char*)As[b] + abase + i * 1024);
#pragma unroll
    for (int j = 0; j < 4; ++j)
      bf[j] = *(const short8*)((const char*)Bs[b] + bbase + j * 1024);
    __builtin_amdgcn_s_setprio(1);
#pragma unroll
    for (int i = 0; i < 8; ++i)
#pragma unroll
      for (int j = 0; j < 4; ++j)
        acc[i][j] = __builtin_amdgcn_mfma_f32_16x16x32_bf16(af[i], bf[j], acc[i][j], 0, 0, 0);
    __builtin_amdgcn_s_setprio(0);
    asm volatile("s_waitcnt lgkmcnt(0)" ::: "memory");
    __builtin_amdgcn_sched_barrier(0);
  }
#pragma unroll
  for (int i = 0; i < 8; ++i)
#pragma unroll
    for (int j = 0; j < 4; ++j)
#pragma unroll
      for (int r = 0; r < 4; ++r) {
        int m = bm + wr + i * 16 + lhi * 4 + r;
        int n = bn + wc + j * 16 + l15;
        C[(size_t)m * kV + n] = __float2bfloat16(acc[i][j][r] + bias[n]);
      }
}

// ---------------- log_softmax: bf16 logits -> fp32 out (unchanged)
__global__ __launch_bounds__(640, 2) void k_lsm_bf(const bf16* __restrict__ L,
                                                   float* __restrict__ y) {
  const bf16* row = L + (size_t)blockIdx.x * kV;
  float* orow = y + (size_t)blockIdx.x * kV;
  const int t = threadIdx.x;
  const bool extra = t < 160;
  float v[56];
  float sum = 0.f;
#pragma unroll
  for (int i = 0; i < 6; ++i) {
    short8 s = *(const short8*)(row + (t + i * 640) * 8);
#pragma unroll
    for (int e = 0; e < 8; ++e) {
      float f = bfu2f(s[e]);
      v[i * 8 + e] = f;
      sum += __expf(f);
    }
  }
  if (extra) {
    short8 s = *(const short8*)(row + (3840 + t) * 8);
#pragma unroll
    for (int e = 0; e < 8; ++e) {
      float f = bfu2f(s[e]);
      v[48 + e] = f;
      sum += __expf(f);
    }
  }
#pragma unroll
  for (int o = 32; o; o >>= 1) sum += __shfl_xor(sum, o);
  __shared__ float red2[10];
  const int w = t >> 6, lane = t & 63;
  if (lane == 0) red2[w] = sum;
  __syncthreads();
  sum = 0.f;
#pragma unroll
  for (int i = 0; i < 10; ++i) sum += red2[i];
  const float sh = logf(sum);
#pragma unroll
  for (int i = 0; i < 6; ++i)
#pragma unroll
    for (int e = 0; e < 8; ++e) orow[(t + i * 640) * 8 + e] = v[i * 8 + e] - sh;
  if (extra)
#pragma unroll
    for (int e = 0; e < 8; ++e) orow[(3840 + t) * 8 + e] = v[48 + e] - sh;
}

extern "C" void kernel_launch(void* const* d_in, const int* in_sizes, int n_in,
                              void* d_out, int out_size, void* d_ws, size_t ws_size,
                              hipStream_t stream) {
  (void)in_sizes; (void)n_in; (void)out_size;
  if (ws_size < (size_t)212 * 1024 * 1024) return;

  const int* src = (const int*)d_in[0];
  const int* tgt = (const int*)d_in[1];
  const float* src_emb   = (const float*)d_in[4];
  const float* tgt_emb   = (const float*)d_in[5];
  const float* enc_attn_w = (const float*)d_in[6];
  const float* enc_attn_b = (const float*)d_in[7];
  const float* enc_ffn_w1 = (const float*)d_in[8];
  const float* enc_ffn_b1 = (const float*)d_in[9];
  const float* enc_ffn_w2 = (const float*)d_in[10];
  const float* enc_ffn_b2 = (const float*)d_in[11];
  const float* enc_ln_g  = (const float*)d_in[12];
  const float* enc_ln_b  = (const float*)d_in[13];
  const float* enc_norm_g = (const float*)d_in[14];
  const float* enc_norm_b = (const float*)d_in[15];
  const float* dec_self_w = (const float*)d_in[16];
  const float* dec_self_b = (const float*)d_in[17];
  const float* dec_cross_w = (const float*)d_in[18];
  const float* dec_cross_b = (const float*)d_in[19];
  const float* dec_ffn_w1 = (const float*)d_in[20];
  const float* dec_ffn_b1 = (const float*)d_in[21];
  const float* dec_ffn_w2 = (const float*)d_in[22];
  const float* dec_ffn_b2 = (const float*)d_in[23];
  const float* dec_ln_g  = (const float*)d_in[24];
  const float* dec_ln_b  = (const float*)d_in[25];
  const float* dec_norm_g = (const float*)d_in[26];
  const float* dec_norm_b = (const float*)d_in[27];
  const float* proj_w    = (const float*)d_in[28];
  const float* proj_b    = (const float*)d_in[29];

  char* ws = (char*)d_ws;
  auto MB = [](size_t x) { return x << 20; };
  bf16* enc_attn_wt  = (bf16*)(ws + MB(0));
  bf16* dec_self_wt  = (bf16*)(ws + MB(4));
  bf16* dec_cross_wt = (bf16*)(ws + MB(8));
  bf16* enc_f1t = (bf16*)(ws + MB(12));
  bf16* enc_f2t = (bf16*)(ws + MB(16));
  bf16* dec_f1t = (bf16*)(ws + MB(20));
  bf16* dec_f2t = (bf16*)(ws + MB(24));
  bf16* proj_wt = (bf16*)(ws + MB(28));
  float* x_enc  = (float*)(ws + MB(60));
  float* x_dec  = (float*)(ws + MB(64));
  bf16* hbuf    = (bf16*)(ws + MB(68));
  bf16* enc_bf  = (bf16*)(ws + MB(70));
  bf16* Qb      = (bf16*)(ws + MB(72));  // Kb at +1Mi elems, VtB at +2Mi
  bf16* attn_o  = (bf16*)(ws + MB(78));
  bf16* logits  = (bf16*)(ws + MB(80));  // 131 MB, up to MB(211)
  bf16* hbuf2   = (bf16*)(ws + MB(208)); // dec l0 LN0/LN2 buffer (survives encoder)
  char* dob = (char*)d_out;
  bf16* ffn_mid = (bf16*)dob;
  bf16* Qb2     = (bf16*)(dob + MB(16)); // 6 MB (Q,K,V^T segments)
  bf16* attn_o2 = (bf16*)(dob + MB(24)); // 2 MB

  // ---- prep: transposes + embed + LN0 (enc l0 LN1 -> hbuf, dec l0 LN1 -> hbuf2)
  PrepArgs P;
  int acc = 0;
  auto setj = [&](int j, const float* s, bf16* d, int K, int N, int z) {
    P.tj.src[j] = s; P.tj.dst[j] = d; P.tj.K[j] = K; P.tj.N[j] = N; P.tj.ofs[j] = acc;
    acc += (K >> 5) * (N >> 5) * z;
  };
  setj(0, enc_attn_w, enc_attn_wt, 512, 512, 8);
  setj(1, dec_self_w, dec_self_wt, 512, 512, 8);
  setj(2, dec_cross_w, dec_cross_wt, 512, 512, 8);
  setj(3, enc_ffn_w1, enc_f1t, 512, 2048, 2);
  setj(4, enc_ffn_w2, enc_f2t, 2048, 512, 2);
  setj(5, dec_ffn_w1, dec_f1t, 512, 2048, 2);
  setj(6, dec_ffn_w2, dec_f2t, 2048, 512, 2);
  setj(7, proj_w, proj_wt, 512, 32000, 1);
  P.tj.ofs[8] = acc;
  P.ntile = acc;
  P.src = src; P.tgt = tgt;
  P.src_emb = src_emb; P.tgt_emb = tgt_emb;
  P.eg = enc_ln_g; P.eb = enc_ln_b;
  P.dg = dec_ln_g; P.db = dec_ln_b;
  P.x_enc = x_enc; P.x_dec = x_dec;
  P.hb_enc = hbuf; P.hb_dec = hbuf2;
  k_prep<<<acc + 2 * kM, 256, 0, stream>>>(P);

  // ---- helpers
  auto qkv = [&](const bf16* aptr, const bf16* wt, const float* bias, const bf16* kvA) {
    if (kvA)
      k_gemm<64, 64, ST_QKV, true, false, false, 3, false, true, false>
          <<<dim3(24, 32, 1), 256, 0, stream>>>(
          aptr, 512, 0, wt, 512, 0, Qb, 0, 0, 512, 1.f, bias, nullptr, kvA,
          nullptr, nullptr, nullptr, nullptr);
    else
      k_gemm<64, 64, ST_QKV, true, false, false, 3, false, false, false>
          <<<dim3(24, 32, 1), 256, 0, stream>>>(
          aptr, 512, 0, wt, 512, 0, Qb, 0, 0, 512, 1.f, bias, nullptr, nullptr,
          nullptr, nullptr, nullptr, nullptr);
  };
  auto fattn = [&](bool causal, const bf16* qb, bf16* ao) {
    if (causal) k_fattn<true><<<dim3(16, kBH), 256, 0, stream>>>(qb, qb + 1048576, qb + 2097152, ao);
    else        k_fattn<false><<<dim3(16, kBH), 256, 0, stream>>>(qb, qb + 1048576, qb + 2097152, ao);
  };
  auto out_proj = [&](const bf16* ao, const bf16* wt, const float* bias, float* xio) {
    k_gemm<32, 64, ST_F32, true, false, true, 3, false, false, false>
        <<<dim3(8, 64, 1), 256, 0, stream>>>(
        ao, 512, 0, wt + 3 * 262144, 512, 0, xio, 512, 0, 512, 1.f, bias + 3 * 512,
        xio, nullptr, nullptr, nullptr, nullptr, nullptr);
  };
  auto LN = [&](const float* x, const float* g, const float* b, bf16* out) {
    k_ln<<<kM / 4, 256, 0, stream>>>(x, g, b, out);
  };
  auto ffn = [&](float* xio, const bf16* w1t, const float* b1, const bf16* w2t,
                 const float* b2) {
    k_gemm<64, 64, ST_BF16, true, true, false, 3, false, false, false>
        <<<dim3(32, 32, 1), 256, 0, stream>>>(
        hbuf, 512, 0, w1t, 512, 0, ffn_mid, kF, 0, 512, 1.f, b1, nullptr, nullptr,
        nullptr, nullptr, nullptr, nullptr);
    k_gemm<32, 64, ST_F32, true, false, true, 3, false, false, false>
        <<<dim3(8, 64, 1), 256, 0, stream>>>(
        ffn_mid, 2048, 0, w2t, 2048, 0, xio, 512, 0, 2048, 1.f, b2, xio, nullptr,
        nullptr, nullptr, nullptr, nullptr);
  };

  // ---- PAIRED phase: enc-l0 attn || dec-l0 self-attn
  k_gemm<64, 64, ST_QKV, true, false, false, 3, false, false, true>
      <<<dim3(24, 64, 1), 256, 0, stream>>>(
      hbuf, 512, 0, enc_attn_wt, 512, 0, Qb, 0, 0, 512, 1.f, enc_attn_b, nullptr,
      hbuf2, dec_self_wt, Qb2, dec_self_b, nullptr);
  k_fattn2<<<dim3(16, 2 * kBH), 256, 0, stream>>>(Qb, attn_o, 0, Qb2, attn_o2, 1);
  k_gemm<32, 64, ST_F32, true, false, true, 3, false, false, true>
      <<<dim3(8, 128, 1), 256, 0, stream>>>(
      attn_o, 512, 0, enc_attn_wt + 3 * 262144, 512, 0, x_enc, 512, 0, 512, 1.f,
      enc_attn_b + 3 * 512, x_enc,
      attn_o2, dec_self_wt + 3 * 262144, x_dec, dec_self_b + 3 * 512, x_dec);
  k_ln2<<<dim3(kM / 4, 2), 256, 0, stream>>>(
      x_enc, enc_ln_g + 512, enc_ln_b + 512, hbuf,
      x_dec, dec_ln_g + 512, dec_ln_b + 512, hbuf2);

  // ---- encoder remainder
  ffn(x_enc, enc_f1t, enc_ffn_b1, enc_f2t, enc_ffn_b2);                 // layer 0 FFN
  LN(x_enc, enc_ln_g + 1024, enc_ln_b + 1024, hbuf);                    // l1 LN1
  qkv(hbuf, enc_attn_wt + 1048576, enc_attn_b + 2048, nullptr);
  fattn(false, Qb, attn_o);
  out_proj(attn_o, enc_attn_wt + 1048576, enc_attn_b + 2048, x_enc);
  LN(x_enc, enc_ln_g + 1024 + 512, enc_ln_b + 1024 + 512, hbuf);        // l1 LN2
  ffn(x_enc, enc_f1t + 1048576, enc_ffn_b1 + 2048, enc_f2t + 1048576, enc_ffn_b2 + 512);
  LN(x_enc, enc_norm_g, enc_norm_b, enc_bf);                            // final LN

  // ---- decoder (l0 resumes at cross-attn; hbuf2 holds LN2(x_dec))
  for (int i = 0; i < 2; ++i) {
    const bf16* wts = dec_self_wt + (size_t)i * 1048576;
    const float* bs = dec_self_b + i * 2048;
    const bf16* wtc = dec_cross_wt + (size_t)i * 1048576;
    const float* bc = dec_cross_b + i * 2048;
    if (i == 1) {
      LN(x_dec, dec_ln_g + 1536, dec_ln_b + 1536, hbuf);                // l1 LN1
      qkv(hbuf, wts, bs, nullptr);
      fattn(true, Qb, attn_o);
      out_proj(attn_o, wts, bs, x_dec);
      LN(x_dec, dec_ln_g + 1536 + 512, dec_ln_b + 1536 + 512, hbuf);    // l1 LN2
    }
    const bf16* qsrc = (i == 0) ? hbuf2 : hbuf;
    qkv(qsrc, wtc, bc, enc_bf);                                         // cross QKV
    fattn(false, Qb, attn_o);
    out_proj(attn_o, wtc, bc, x_dec);
    LN(x_dec, dec_ln_g + i * 1536 + 1024, dec_ln_b + i * 1536 + 1024, hbuf);  // LN3
    ffn(x_dec, dec_f1t + (size_t)i * 1048576, dec_ffn_b1 + i * 2048,
        dec_f2t + (size_t)i * 1048576, dec_ffn_b2 + i * 512);
  }
  LN(x_dec, dec_norm_g, dec_norm_b, hbuf);                              // final LN

  // logits -> log_softmax
  k_proj256<<<dim3(125, 8), 512, 0, stream>>>(hbuf, proj_wt, logits, proj_b);
  k_lsm_bf<<<kM, 640, 0, stream>>>(logits, (float*)d_out);
}

// Round 18
// 644.330 us; speedup vs baseline: 1.5999x; 1.0013x over previous
//
#include <hip/hip_runtime.h>
#include <hip/hip_bf16.h>
#include <math.h>

using bf16 = __hip_bfloat16;
typedef float f32x4 __attribute__((ext_vector_type(4)));
typedef short short8 __attribute__((ext_vector_type(8)));

constexpr int kD = 512, kH = 8, kDk = 64, kF = 2048, kV = 32000;
constexpr int kB = 2, kS = 1024, kM = 2048, kBH = 16;  // kM = B*S tokens

enum { ST_F32 = 0, ST_BF16, ST_QKV };

__device__ __forceinline__ void gload_lds16(const void* g, void* l) {
  __builtin_amdgcn_global_load_lds(
      (const __attribute__((address_space(1))) void*)g,
      (__attribute__((address_space(3))) void*)l, 16, 0, 0);
}

__device__ __forceinline__ float bfu2f(short u) {
  union { unsigned int i; float f; } c;
  c.i = ((unsigned int)(unsigned short)u) << 16;
  return c.f;
}

// ---------------- generic MFMA GEMM: C = A[M,K] @ Bt[N,K]^T (+bias)(+relu)(+res)
// BMxBN tiles, 4 waves (2x2), 3-deep counted-vmcnt pipeline, XOR-swizzled LDS (R13).
// DUAL: grid.y doubled; upper half switches {A,Bt,Cv,bias,res} to job 2.
// ASEL: blocks with bn>=512 read A2 (cross-attn Q/KV source split).
// R18: T5 setprio around the MFMA cluster (multi-block/CU cross-phase arbitration).
template <int BM, int BN, int STM, bool BIAS, bool RELU, bool RES, int NBUF, bool XSWZ,
          bool ASEL, bool DUAL>
__launch_bounds__(256)
__global__ void k_gemm(const bf16* __restrict__ A, int lda, long long Az,
                       const bf16* __restrict__ Bt, int ldb, long long Bz,
                       void* __restrict__ Cv, int ldc, long long Cz,
                       int K, float alpha,
                       const float* __restrict__ bias,
                       const float* __restrict__ res,
                       const bf16* __restrict__ A2,
                       const bf16* __restrict__ Bt2,
                       void* __restrict__ Cv2,
                       const float* __restrict__ bias2,
                       const float* __restrict__ res2) {
  constexpr int FM = BM / 32, FN = BN / 32;
  constexpr int LPS = BM / 32 + BN / 32;   // global_load_lds per stage
  __shared__ __attribute__((aligned(16))) bf16 As[NBUF][BM * 64];
  __shared__ __attribute__((aligned(16))) bf16 Bs[NBUF][BN * 64];
  const int tid = threadIdx.x;
  const int w = tid >> 6, lane = tid & 63;
  int bx = blockIdx.x, by = blockIdx.y;
  if constexpr (DUAL) {
    const int half = gridDim.y >> 1;
    if (by >= half) {
      by -= half;
      A = A2; Bt = Bt2; Cv = Cv2; bias = bias2; res = res2;
    }
  }
  if constexpr (XSWZ) {
    const int nx = gridDim.x, ny = gridDim.y;
    const int lin = by * nx + bx;
    const int cpx = (nx * ny) >> 3;
    const int s = (lin & 7) * cpx + (lin >> 3);
    bx = s / ny;
    by = s - bx * ny;
  }
  const int bm = by * BM, bn = bx * BN;
  const int z = blockIdx.z;
  if constexpr (ASEL) { if (bn >= 512) A = A2; }
  A += (long long)z * Az;
  Bt += (long long)z * Bz;
  const int l15 = lane & 15, lhi = lane >> 4;
  const int wr = (w >> 1) * (BM / 2), wc = (w & 1) * (BN / 2);
  f32x4 acc[FM][FN] = {};
  const int nkt = K >> 6;  // BK = 64

  auto stage = [&](int kt, int nb) {
#pragma unroll
    for (int it = 0; it < BM / 32; ++it) {
      int chunk = (it * 4 + w) * 64 + lane;        // 16B chunks, LDS-linear dest
      int row = chunk >> 3, c = chunk & 7;
      int col = (c ^ (row & 7)) << 3;              // pre-swizzled global source
      gload_lds16(A + (size_t)(bm + row) * lda + kt * 64 + col, As[nb] + (it * 4 + w) * 512);
    }
#pragma unroll
    for (int it = 0; it < BN / 32; ++it) {
      int chunk = (it * 4 + w) * 64 + lane;
      int row = chunk >> 3, c = chunk & 7;
      int col = (c ^ (row & 7)) << 3;
      gload_lds16(Bt + (size_t)(bn + row) * ldb + kt * 64 + col, Bs[nb] + (it * 4 + w) * 512);
    }
  };
  auto waitSteady = [&]() {
    if constexpr (LPS == 3) asm volatile("s_waitcnt vmcnt(6)" ::: "memory");
    else                    asm volatile("s_waitcnt vmcnt(8)" ::: "memory");
  };
  auto compute = [&](int cb) {
#pragma unroll
    for (int kk = 0; kk < 2; ++kk) {
      short8 af[FM], bf[FN];
#pragma unroll
      for (int i = 0; i < FM; ++i) {
        int row = wr + i * 16 + l15;
        af[i] = *(const short8*)(As[cb] + row * 64 + (((kk * 4 + lhi) ^ (row & 7)) * 8));
      }
#pragma unroll
      for (int j = 0; j < FN; ++j) {
        int row = wc + j * 16 + l15;
        bf[j] = *(const short8*)(Bs[cb] + row * 64 + (((kk * 4 + lhi) ^ (row & 7)) * 8));
      }
      __builtin_amdgcn_s_setprio(1);
#pragma unroll
      for (int i = 0; i < FM; ++i)
#pragma unroll
        for (int j = 0; j < FN; ++j)
          acc[i][j] = __builtin_amdgcn_mfma_f32_16x16x32_bf16(af[i], bf[j], acc[i][j], 0, 0, 0);
      __builtin_amdgcn_s_setprio(0);
    }
  };

  if constexpr (NBUF == 3) {
    stage(0, 0);
    stage(1, 1);
    stage(2, 2);                                   // 3*LPS loads out
    waitSteady();                                  // tile0 landed
    __builtin_amdgcn_s_barrier();
    __builtin_amdgcn_sched_barrier(0);
    int cur = 0;
    for (int kt = 0; kt < nkt; ++kt) {
      compute(cur);
      asm volatile("s_waitcnt lgkmcnt(0)" ::: "memory");  // ds_reads of buf[cur] done
      __builtin_amdgcn_sched_barrier(0);
      if (kt + 1 < nkt) {
        __builtin_amdgcn_s_barrier();        // all waves done reading buf[cur]
        if (kt + 3 < nkt) {
          stage(kt + 3, cur);                // overwrite buf[cur]
          waitSteady();                      // stage(kt+1) landed
        } else {
          asm volatile("s_waitcnt vmcnt(0)" ::: "memory");
        }
        __builtin_amdgcn_s_barrier();        // all waves confirm next buf ready
        __builtin_amdgcn_sched_barrier(0);
      }
      cur = (cur == 2) ? 0 : cur + 1;
    }
  } else {
    for (int kt = 0; kt < nkt; ++kt) {
      stage(kt, 0);
      __syncthreads();
      compute(0);
      __syncthreads();
    }
  }

  // epilogue: C/D layout col=lane&15, row=(lane>>4)*4+r (m89-verified)
#pragma unroll
  for (int i = 0; i < FM; ++i) {
#pragma unroll
    for (int j = 0; j < FN; ++j) {
#pragma unroll
      for (int r = 0; r < 4; ++r) {
        int m = bm + wr + i * 16 + lhi * 4 + r;
        int n = bn + wc + j * 16 + l15;
        float val = acc[i][j][r] * alpha;
        if constexpr (BIAS) val += bias[n];
        if constexpr (RELU) val = fmaxf(val, 0.f);
        if constexpr (RES) val += res[(size_t)m * ldc + n];
        if constexpr (STM == ST_F32) {
          ((float*)Cv)[(size_t)z * Cz + (size_t)m * ldc + n] = val;
        } else if constexpr (STM == ST_BF16) {
          ((bf16*)Cv)[(size_t)z * Cz + (size_t)m * ldc + n] = __float2bfloat16(val);
        } else if constexpr (STM == ST_QKV) {    // n<512->Q, <1024->K (both [B,H,S,dk]), else V^T [B,H,dk,S]
          int seg = n >> 9, nn = n & 511;
          int b_ = m >> 10, s_ = m & 1023, h_ = nn >> 6, d_ = nn & 63;
          size_t idx = (seg < 2)
              ? (((size_t)(b_ * kH + h_) << 10) + s_) * kDk + d_
              : ((size_t)(b_ * kH + h_) * kDk + d_) * kS + s_;
          ((bf16*)Cv)[(size_t)seg * 1048576 + idx] = __float2bfloat16(val);
        }
      }
    }
  }
}

// ---------------- fused flash attention core (R13 body + T5 setprio around MFMA).
__device__ __forceinline__ void fattn_body(const bf16* __restrict__ Q,
                                           const bf16* __restrict__ K,
                                           const bf16* __restrict__ Vt,
                                           bf16* __restrict__ O,
                                           int q0, int bh, bool causal,
                                           bf16 (*Ks)[4096], bf16 (*Vs)[4096],
                                           bf16 (*Ps)[1024]) {
  const int tid = threadIdx.x, w = tid >> 6, lane = tid & 63;
  const int l15 = lane & 15, lhi = lane >> 4;
  const int qw = q0 + w * 16;
  const bf16* Qp = Q + (((size_t)(bh << 10)) + qw + l15) * kDk;
  short8 aq[2];
  aq[0] = *(const short8*)(Qp + lhi * 8);
  aq[1] = *(const short8*)(Qp + 32 + lhi * 8);
  const int srow = w * 8 + (lane >> 3);
  const int sc = (lane & 7) ^ (srow & 7);
  const bf16* Ksrc = K + (((size_t)(bh << 10)) + srow) * kDk + sc * 8;
  const bf16* Vsrc = Vt + ((size_t)bh * kDk + srow) * kS + sc * 8;
  const int nt = causal ? (q0 >> 6) + 1 : (kS >> 6);

  auto stage = [&](int t, int nb) {
    int kv0 = t << 6;
    gload_lds16(Ksrc + (size_t)kv0 * kDk, Ks[nb] + w * 512);
    gload_lds16(Ksrc + (size_t)(kv0 + 32) * kDk, Ks[nb] + 2048 + w * 512);
    gload_lds16(Vsrc + kv0, Vs[nb] + w * 512);
    gload_lds16(Vsrc + kv0 + 32 * kS, Vs[nb] + 2048 + w * 512);
  };

  float m_[4], l_[4];
#pragma unroll
  for (int r = 0; r < 4; ++r) { m_[r] = -1e30f; l_[r] = 0.f; }
  f32x4 ao[4] = {};

  stage(0, 0);
  if (nt > 2) {
    stage(1, 1);
    stage(2, 2);
    asm volatile("s_waitcnt vmcnt(8)" ::: "memory");
  } else if (nt > 1) {
    stage(1, 1);
    asm volatile("s_waitcnt vmcnt(4)" ::: "memory");
  } else {
    asm volatile("s_waitcnt vmcnt(0)" ::: "memory");
  }
  __builtin_amdgcn_s_barrier();
  __builtin_amdgcn_sched_barrier(0);

  int cur = 0;
  for (int t = 0; t < nt; ++t) {
    f32x4 as[4] = {};
    __builtin_amdgcn_s_setprio(1);
#pragma unroll
    for (int kk = 0; kk < 2; ++kk) {
      short8 bk[4];
#pragma unroll
      for (int nf = 0; nf < 4; ++nf) {
        int row = nf * 16 + l15;
        int c = (4 * kk + lhi) ^ (row & 7);
        bk[nf] = *(const short8*)(Ks[cur] + row * 64 + c * 8);
      }
#pragma unroll
      for (int nf = 0; nf < 4; ++nf)
        as[nf] = __builtin_amdgcn_mfma_f32_16x16x32_bf16(aq[kk], bk[nf], as[nf], 0, 0, 0);
    }
    __builtin_amdgcn_s_setprio(0);
    float s[4][4];
#pragma unroll
    for (int nf = 0; nf < 4; ++nf)
#pragma unroll
      for (int r = 0; r < 4; ++r) {
        float v = as[nf][r] * 0.125f;
        if (causal && t == nt - 1) {
          int col = (t << 6) + nf * 16 + l15;
          int row = qw + lhi * 4 + r;
          if (col > row) v = -1e30f;
        }
        s[nf][r] = v;
      }
    float mn[4], scl[4], rsum[4];
#pragma unroll
    for (int r = 0; r < 4; ++r) {
      float mx = fmaxf(fmaxf(s[0][r], s[1][r]), fmaxf(s[2][r], s[3][r]));
      mx = fmaxf(mx, __shfl_xor(mx, 1));
      mx = fmaxf(mx, __shfl_xor(mx, 2));
      mx = fmaxf(mx, __shfl_xor(mx, 4));
      mx = fmaxf(mx, __shfl_xor(mx, 8));
      mn[r] = fmaxf(m_[r], mx);
      scl[r] = __expf(m_[r] - mn[r]);
      rsum[r] = 0.f;
    }
#pragma unroll
    for (int nf = 0; nf < 4; ++nf)
#pragma unroll
      for (int r = 0; r < 4; ++r) {
        float p = __expf(s[nf][r] - mn[r]);
        rsum[r] += p;
        int pr = lhi * 4 + r;
        int c = (2 * nf + (l15 >> 3)) ^ (pr & 7);
        Ps[w][pr * 64 + c * 8 + (l15 & 7)] = __float2bfloat16(p);
      }
#pragma unroll
    for (int r = 0; r < 4; ++r) {
      float su = rsum[r];
      su += __shfl_xor(su, 1);
      su += __shfl_xor(su, 2);
      su += __shfl_xor(su, 4);
      su += __shfl_xor(su, 8);
      l_[r] = l_[r] * scl[r] + su;
      m_[r] = mn[r];
    }
#pragma unroll
    for (int nf = 0; nf < 4; ++nf)
#pragma unroll
      for (int r = 0; r < 4; ++r) ao[nf][r] *= scl[r];
    asm volatile("s_waitcnt lgkmcnt(0)" ::: "memory");
    __builtin_amdgcn_sched_barrier(0);
    __builtin_amdgcn_s_setprio(1);
#pragma unroll
    for (int kk = 0; kk < 2; ++kk) {
      short8 pa = *(const short8*)(Ps[w] + l15 * 64 + (((4 * kk + lhi) ^ (l15 & 7)) * 8));
      short8 bv[4];
#pragma unroll
      for (int nf = 0; nf < 4; ++nf) {
        int row = nf * 16 + l15;
        int c = (4 * kk + lhi) ^ (row & 7);
        bv[nf] = *(const short8*)(Vs[cur] + row * 64 + c * 8);
      }
#pragma unroll
      for (int nf = 0; nf < 4; ++nf)
        ao[nf] = __builtin_amdgcn_mfma_f32_16x16x32_bf16(pa, bv[nf], ao[nf], 0, 0, 0);
    }
    __builtin_amdgcn_s_setprio(0);
    asm volatile("s_waitcnt lgkmcnt(0)" ::: "memory");
    __builtin_amdgcn_sched_barrier(0);
    if (t + 1 < nt) {
      __builtin_amdgcn_s_barrier();
      if (t + 3 < nt) {
        stage(t + 3, cur);
        asm volatile("s_waitcnt vmcnt(8)" ::: "memory");
      } else {
        asm volatile("s_waitcnt vmcnt(0)" ::: "memory");
      }
      __builtin_amdgcn_s_barrier();
      __builtin_amdgcn_sched_barrier(0);
    }
    cur = (cur == 2) ? 0 : cur + 1;
  }
  const int b_ = bh >> 3, h_ = bh & 7;
  float inv[4];
#pragma unroll
  for (int r = 0; r < 4; ++r) inv[r] = 1.f / l_[r];
#pragma unroll
  for (int nf = 0; nf < 4; ++nf)
#pragma unroll
    for (int r = 0; r < 4; ++r) {
      int q = qw + lhi * 4 + r;
      O[((size_t)(b_ * kS + q)) * kD + h_ * kDk + nf * 16 + l15] =
          __float2bfloat16(ao[nf][r] * inv[r]);
    }
}

template <bool CAUSAL>
__launch_bounds__(256)
__global__ void k_fattn(const bf16* __restrict__ Q, const bf16* __restrict__ K,
                        const bf16* __restrict__ Vt, bf16* __restrict__ O) {
  __shared__ __attribute__((aligned(16))) bf16 Ks[3][4096];
  __shared__ __attribute__((aligned(16))) bf16 Vs[3][4096];
  __shared__ __attribute__((aligned(16))) bf16 Ps[4][1024];
  fattn_body(Q, K, Vt, O, blockIdx.x * 64, blockIdx.y, CAUSAL, Ks, Vs, Ps);
}

// dual-job flash attention: grid (16, 2*kBH); upper half = job 2 (own Q/K/V/O + causal2)
__launch_bounds__(256)
__global__ void k_fattn2(const bf16* __restrict__ Q1, bf16* __restrict__ O1, int c1,
                         const bf16* __restrict__ Q2, bf16* __restrict__ O2, int c2) {
  __shared__ __attribute__((aligned(16))) bf16 Ks[3][4096];
  __shared__ __attribute__((aligned(16))) bf16 Vs[3][4096];
  __shared__ __attribute__((aligned(16))) bf16 Ps[4][1024];
  int by = blockIdx.y;
  const bf16* Q = Q1; bf16* O = O1; bool causal = c1;
  if (by >= kBH) { by -= kBH; Q = Q2; O = O2; causal = c2; }
  fattn_body(Q, Q + 1048576, Q + 2097152, O, blockIdx.x * 64, by, causal, Ks, Vs, Ps);
}

// ---------------- prep: weight transposes + embed(+inline LN0), 1 launch (R14-verified)
struct TJobs {
  const float* src[8];
  bf16* dst[8];
  int K[8], N[8];
  int ofs[9];
};

struct PrepArgs {
  TJobs tj; int ntile;
  const int *src, *tgt;
  const float *src_emb, *tgt_emb;
  const float *eg, *eb, *dg, *db;   // first-LN params (enc l0, dec l0)
  float *x_enc, *x_dec;
  bf16 *hb_enc, *hb_dec;
};

__global__ void k_prep(PrepArgs P) {
  __shared__ float t[32][33];
  __shared__ float red[4], red2[4];
  const int tid = threadIdx.x;
  if ((int)blockIdx.x < P.ntile) {
    const int tb = blockIdx.x;
    int j = 0;
#pragma unroll
    for (int i = 1; i < 8; ++i) j += (tb >= P.tj.ofs[i]) ? 1 : 0;
    const int K = P.tj.K[j], N = P.tj.N[j];
    const int tn = N >> 5, tk = K >> 5;
    int r = tb - P.tj.ofs[j];
    const int z = r / (tn * tk);
    r -= z * tn * tk;
    const int k0 = (r / tn) << 5, n0 = (r % tn) << 5;
    const float* Wp = P.tj.src[j] + (size_t)z * K * N;
    bf16* WTp = P.tj.dst[j] + (size_t)z * K * N;
    const int tx = tid & 31, ty = tid >> 5;
#pragma unroll
    for (int rr = 0; rr < 32; rr += 8)
      t[ty + rr][tx] = Wp[(size_t)(k0 + ty + rr) * N + n0 + tx];
    __syncthreads();
#pragma unroll
    for (int rr = 0; rr < 32; rr += 8)
      WTp[(size_t)(n0 + ty + rr) * K + k0 + tx] = __float2bfloat16(t[tx][ty + rr]);
    return;
  }
  // embed + inline LN: block owns one full token row
  const int vb = blockIdx.x - P.ntile;
  const int m = vb & (kM - 1), which = vb >> 11;
  const int* tok = which ? P.tgt : P.src;
  const float* emb = which ? P.tgt_emb : P.src_emb;
  float* x = which ? P.x_dec : P.x_enc;
  const int s = m & (kS - 1);
  const float* e = emb + (size_t)tok[m] * kD;
  float* xp = x + (size_t)m * kD;
  float v[2];
#pragma unroll
  for (int h = 0; h < 2; ++h) {
    int d = tid + h * 256;
    int i = d >> 1;
    float freq = __expf(-(float)(2 * i) * (9.210340371976184f / 512.0f));
    float ang = (float)s * freq;
    float pe = (d & 1) ? cosf(ang) : sinf(ang);
    v[h] = e[d] * 22.62741699796952f + pe;
    xp[d] = v[h];
  }
  const int w = tid >> 6, lane = tid & 63;
  float sum = v[0] + v[1];
#pragma unroll
  for (int o = 32; o; o >>= 1) sum += __shfl_xor(sum, o);
  if (lane == 0) red[w] = sum;
  __syncthreads();
  sum = red[0] + red[1] + red[2] + red[3];
  const float mean = sum * (1.f / 512.f);
  float sq = (v[0] - mean) * (v[0] - mean) + (v[1] - mean) * (v[1] - mean);
#pragma unroll
  for (int o = 32; o; o >>= 1) sq += __shfl_xor(sq, o);
  if (lane == 0) red2[w] = sq;
  __syncthreads();
  sq = red2[0] + red2[1] + red2[2] + red2[3];
  const float rstd = rsqrtf(sq * (1.f / 511.f) + 1e-6f);
  const float* g = which ? P.dg : P.eg;
  const float* b = which ? P.db : P.eb;
  bf16* hb = (which ? P.hb_dec : P.hb_enc) + (size_t)m * kD;
#pragma unroll
  for (int h = 0; h < 2; ++h) {
    int d = tid + h * 256;
    hb[d] = __float2bfloat16(g[d] * (v[h] - mean) * rstd + b[d]);
  }
}

// ---------------- LayerNorm (unbiased var /511, eps 1e-6), fp32 in -> bf16 out. wave/row.
__global__ void k_ln(const float* __restrict__ x, const float* __restrict__ g,
                     const float* __restrict__ b, bf16* __restrict__ out) {
  int w = threadIdx.x >> 6, lane = threadIdx.x & 63;
  int row = blockIdx.x * 4 + w;
  const float* xp = x + (size_t)row * kD;
  float v[8];
  float sum = 0.f;
#pragma unroll
  for (int i = 0; i < 8; ++i) { v[i] = xp[lane + i * 64]; sum += v[i]; }
#pragma unroll
  for (int o = 32; o; o >>= 1) sum += __shfl_xor(sum, o);
  float mean = sum * (1.f / 512.f);
  float sq = 0.f;
#pragma unroll
  for (int i = 0; i < 8; ++i) { float d = v[i] - mean; sq += d * d; }
#pragma unroll
  for (int o = 32; o; o >>= 1) sq += __shfl_xor(sq, o);
  float inv = rsqrtf(sq * (1.f / 511.f) + 1e-6f);
  bf16* op = out + (size_t)row * kD;
#pragma unroll
  for (int i = 0; i < 8; ++i) {
    int d = lane + i * 64;
    op[d] = __float2bfloat16(g[d] * (v[i] - mean) * inv + b[d]);
  }
}

// ---------------- dual LayerNorm: grid (512, 2); y selects job
__global__ void k_ln2(const float* __restrict__ x1, const float* __restrict__ g1,
                      const float* __restrict__ b1, bf16* __restrict__ o1,
                      const float* __restrict__ x2, const float* __restrict__ g2,
                      const float* __restrict__ b2, bf16* __restrict__ o2) {
  const int which = blockIdx.y;
  const float* x = which ? x2 : x1;
  const float* g = which ? g2 : g1;
  const float* b = which ? b2 : b1;
  bf16* out = which ? o2 : o1;
  int w = threadIdx.x >> 6, lane = threadIdx.x & 63;
  int row = blockIdx.x * 4 + w;
  const float* xp = x + (size_t)row * kD;
  float v[8];
  float sum = 0.f;
#pragma unroll
  for (int i = 0; i < 8; ++i) { v[i] = xp[lane + i * 64]; sum += v[i]; }
#pragma unroll
  for (int o = 32; o; o >>= 1) sum += __shfl_xor(sum, o);
  float mean = sum * (1.f / 512.f);
  float sq = 0.f;
#pragma unroll
  for (int i = 0; i < 8; ++i) { float d = v[i] - mean; sq += d * d; }
#pragma unroll
  for (int o = 32; o; o >>= 1) sq += __shfl_xor(sq, o);
  float inv = rsqrtf(sq * (1.f / 511.f) + 1e-6f);
  bf16* op = out + (size_t)row * kD;
#pragma unroll
  for (int i = 0; i < 8; ++i) {
    int d = lane + i * 64;
    op[d] = __float2bfloat16(g[d] * (v[i] - mean) * inv + b[d]);
  }
}

// ---------------- 256^2-tile proj GEMM (+T5 setprio)
__global__ __launch_bounds__(512, 1) void k_proj256(const bf16* __restrict__ A,
                                                    const bf16* __restrict__ Bt,
                                                    bf16* __restrict__ C,
                                                    const float* __restrict__ bias) {
  __shared__ __attribute__((aligned(16))) bf16 As[4][256 * 32];
  __shared__ __attribute__((aligned(16))) bf16 Bs[4][256 * 32];
  const int tid = threadIdx.x, w = tid >> 6, lane = tid & 63;
  const int l15 = lane & 15, lhi = lane >> 4;
  const int lin = blockIdx.y * 125 + blockIdx.x;
  const int s = (lin & 7) * 125 + (lin >> 3);
  const int bx = s >> 3, by = s & 7;
  const int bm = by * 256, bn = bx * 256;
  const int wr = (w >> 2) * 128, wc = (w & 3) * 64;
  const int rowq = tid >> 2, chk = tid & 3;
  const int swz = (chk ^ ((rowq >> 1) & 3)) << 3;
  const bf16* Asrc0 = A + (size_t)(bm + rowq) * kD + swz;
  const bf16* Asrc1 = A + (size_t)(bm + 128 + rowq) * kD + swz;
  const bf16* Bsrc0 = Bt + (size_t)(bn + rowq) * kD + swz;
  const bf16* Bsrc1 = Bt + (size_t)(bn + 128 + rowq) * kD + swz;
  const int ldsoff = w * 1024;

  auto stage = [&](int kt) {
    const int b = kt & 3;
    const int ko = kt * 32;
    gload_lds16(Asrc0 + ko, (char*)As[b] + ldsoff);
    gload_lds16(Asrc1 + ko, (char*)As[b] + 8192 + ldsoff);
    gload_lds16(Bsrc0 + ko, (char*)Bs[b] + ldsoff);
    gload_lds16(Bsrc1 + ko, (char*)Bs[b] + 8192 + ldsoff);
  };

  const int ra = wr + l15, rb = wc + l15;
  const int abase = ra * 64 + ((lhi ^ ((ra >> 1) & 3)) << 4);
  const int bbase = rb * 64 + ((lhi ^ ((rb >> 1) & 3)) << 4);

  f32x4 acc[8][4] = {};
  stage(0); stage(1); stage(2);
  for (int kt = 0; kt < 16; ++kt) {
    if (kt + 2 < 16)      asm volatile("s_waitcnt vmcnt(8)" ::: "memory");
    else if (kt + 1 < 16) asm volatile("s_waitcnt vmcnt(4)" ::: "memory");
    else                  asm volatile("s_waitcnt vmcnt(0)" ::: "memory");
    __builtin_amdgcn_s_barrier();
    __builtin_amdgcn_sched_barrier(0);
    if (kt + 3 < 16) stage(kt + 3);
    const int b = kt & 3;
    short8 af[8], bf[4];
#pragma unroll
    for (int i = 0; i < 8; ++i)
      af[i] = *(const short8*)((const char*)As[b] + abase + i * 1024);
#pragma unroll
    for (int j = 0; j < 4; ++j)
      bf[j] = *(const short8*)((const char*)Bs[b] + bbase + j * 1024);
    __builtin_amdgcn_s_setprio(1);
#pragma unroll
    for (int i = 0; i < 8; ++i)
#pragma unroll
      for (int j = 0; j < 4; ++j)
        acc[i][j] = __builtin_amdgcn_mfma_f32_16x16x32_bf16(af[i], bf[j], acc[i][j], 0, 0, 0);
    __builtin_amdgcn_s_setprio(0);
    asm volatile("s_waitcnt lgkmcnt(0)" ::: "memory");
    __builtin_amdgcn_sched_barrier(0);
  }
#pragma unroll
  for (int i = 0; i < 8; ++i)
#pragma unroll
    for (int j = 0; j < 4; ++j)
#pragma unroll
      for (int r = 0; r < 4; ++r) {
        int m = bm + wr + i * 16 + lhi * 4 + r;
        int n = bn + wc + j * 16 + l15;
        C[(size_t)m * kV + n] = __float2bfloat16(acc[i][j][r] + bias[n]);
      }
}

// ---------------- log_softmax: bf16 logits -> fp32 out (unchanged)
__global__ __launch_bounds__(640, 2) void k_lsm_bf(const bf16* __restrict__ L,
                                                   float* __restrict__ y) {
  const bf16* row = L + (size_t)blockIdx.x * kV;
  float* orow = y + (size_t)blockIdx.x * kV;
  const int t = threadIdx.x;
  const bool extra = t < 160;
  float v[56];
  float sum = 0.f;
#pragma unroll
  for (int i = 0; i < 6; ++i) {
    short8 s = *(const short8*)(row + (t + i * 640) * 8);
#pragma unroll
    for (int e = 0; e < 8; ++e) {
      float f = bfu2f(s[e]);
      v[i * 8 + e] = f;
      sum += __expf(f);
    }
  }
  if (extra) {
    short8 s = *(const short8*)(row + (3840 + t) * 8);
#pragma unroll
    for (int e = 0; e < 8; ++e) {
      float f = bfu2f(s[e]);
      v[48 + e] = f;
      sum += __expf(f);
    }
  }
#pragma unroll
  for (int o = 32; o; o >>= 1) sum += __shfl_xor(sum, o);
  __shared__ float red2[10];
  const int w = t >> 6, lane = t & 63;
  if (lane == 0) red2[w] = sum;
  __syncthreads();
  sum = 0.f;
#pragma unroll
  for (int i = 0; i < 10; ++i) sum += red2[i];
  const float sh = logf(sum);
#pragma unroll
  for (int i = 0; i < 6; ++i)
#pragma unroll
    for (int e = 0; e < 8; ++e) orow[(t + i * 640) * 8 + e] = v[i * 8 + e] - sh;
  if (extra)
#pragma unroll
    for (int e = 0; e < 8; ++e) orow[(3840 + t) * 8 + e] = v[48 + e] - sh;
}

extern "C" void kernel_launch(void* const* d_in, const int* in_sizes, int n_in,
                              void* d_out, int out_size, void* d_ws, size_t ws_size,
                              hipStream_t stream) {
  (void)in_sizes; (void)n_in; (void)out_size;
  if (ws_size < (size_t)212 * 1024 * 1024) return;

  const int* src = (const int*)d_in[0];
  const int* tgt = (const int*)d_in[1];
  const float* src_emb   = (const float*)d_in[4];
  const float* tgt_emb   = (const float*)d_in[5];
  const float* enc_attn_w = (const float*)d_in[6];
  const float* enc_attn_b = (const float*)d_in[7];
  const float* enc_ffn_w1 = (const float*)d_in[8];
  const float* enc_ffn_b1 = (const float*)d_in[9];
  const float* enc_ffn_w2 = (const float*)d_in[10];
  const float* enc_ffn_b2 = (const float*)d_in[11];
  const float* enc_ln_g  = (const float*)d_in[12];
  const float* enc_ln_b  = (const float*)d_in[13];
  const float* enc_norm_g = (const float*)d_in[14];
  const float* enc_norm_b = (const float*)d_in[15];
  const float* dec_self_w = (const float*)d_in[16];
  const float* dec_self_b = (const float*)d_in[17];
  const float* dec_cross_w = (const float*)d_in[18];
  const float* dec_cross_b = (const float*)d_in[19];
  const float* dec_ffn_w1 = (const float*)d_in[20];
  const float* dec_ffn_b1 = (const float*)d_in[21];
  const float* dec_ffn_w2 = (const float*)d_in[22];
  const float* dec_ffn_b2 = (const float*)d_in[23];
  const float* dec_ln_g  = (const float*)d_in[24];
  const float* dec_ln_b  = (const float*)d_in[25];
  const float* dec_norm_g = (const float*)d_in[26];
  const float* dec_norm_b = (const float*)d_in[27];
  const float* proj_w    = (const float*)d_in[28];
  const float* proj_b    = (const float*)d_in[29];

  char* ws = (char*)d_ws;
  auto MB = [](size_t x) { return x << 20; };
  bf16* enc_attn_wt  = (bf16*)(ws + MB(0));
  bf16* dec_self_wt  = (bf16*)(ws + MB(4));
  bf16* dec_cross_wt = (bf16*)(ws + MB(8));
  bf16* enc_f1t = (bf16*)(ws + MB(12));
  bf16* enc_f2t = (bf16*)(ws + MB(16));
  bf16* dec_f1t = (bf16*)(ws + MB(20));
  bf16* dec_f2t = (bf16*)(ws + MB(24));
  bf16* proj_wt = (bf16*)(ws + MB(28));
  float* x_enc  = (float*)(ws + MB(60));
  float* x_dec  = (float*)(ws + MB(64));
  bf16* hbuf    = (bf16*)(ws + MB(68));
  bf16* enc_bf  = (bf16*)(ws + MB(70));
  bf16* Qb      = (bf16*)(ws + MB(72));  // Kb at +1Mi elems, VtB at +2Mi
  bf16* attn_o  = (bf16*)(ws + MB(78));
  bf16* logits  = (bf16*)(ws + MB(80));  // 131 MB, up to MB(211)
  bf16* hbuf2   = (bf16*)(ws + MB(208)); // dec l0 LN0/LN2 buffer (survives encoder)
  char* dob = (char*)d_out;
  bf16* ffn_mid = (bf16*)dob;
  bf16* Qb2     = (bf16*)(dob + MB(16)); // 6 MB (Q,K,V^T segments)
  bf16* attn_o2 = (bf16*)(dob + MB(24)); // 2 MB

  // ---- prep: transposes + embed + LN0 (enc l0 LN1 -> hbuf, dec l0 LN1 -> hbuf2)
  PrepArgs P;
  int acc = 0;
  auto setj = [&](int j, const float* s, bf16* d, int K, int N, int z) {
    P.tj.src[j] = s; P.tj.dst[j] = d; P.tj.K[j] = K; P.tj.N[j] = N; P.tj.ofs[j] = acc;
    acc += (K >> 5) * (N >> 5) * z;
  };
  setj(0, enc_attn_w, enc_attn_wt, 512, 512, 8);
  setj(1, dec_self_w, dec_self_wt, 512, 512, 8);
  setj(2, dec_cross_w, dec_cross_wt, 512, 512, 8);
  setj(3, enc_ffn_w1, enc_f1t, 512, 2048, 2);
  setj(4, enc_ffn_w2, enc_f2t, 2048, 512, 2);
  setj(5, dec_ffn_w1, dec_f1t, 512, 2048, 2);
  setj(6, dec_ffn_w2, dec_f2t, 2048, 512, 2);
  setj(7, proj_w, proj_wt, 512, 32000, 1);
  P.tj.ofs[8] = acc;
  P.ntile = acc;
  P.src = src; P.tgt = tgt;
  P.src_emb = src_emb; P.tgt_emb = tgt_emb;
  P.eg = enc_ln_g; P.eb = enc_ln_b;
  P.dg = dec_ln_g; P.db = dec_ln_b;
  P.x_enc = x_enc; P.x_dec = x_dec;
  P.hb_enc = hbuf; P.hb_dec = hbuf2;
  k_prep<<<acc + 2 * kM, 256, 0, stream>>>(P);

  // ---- helpers
  auto qkv = [&](const bf16* aptr, const bf16* wt, const float* bias, const bf16* kvA) {
    if (kvA)
      k_gemm<64, 64, ST_QKV, true, false, false, 3, false, true, false>
          <<<dim3(24, 32, 1), 256, 0, stream>>>(
          aptr, 512, 0, wt, 512, 0, Qb, 0, 0, 512, 1.f, bias, nullptr, kvA,
          nullptr, nullptr, nullptr, nullptr);
    else
      k_gemm<64, 64, ST_QKV, true, false, false, 3, false, false, false>
          <<<dim3(24, 32, 1), 256, 0, stream>>>(
          aptr, 512, 0, wt, 512, 0, Qb, 0, 0, 512, 1.f, bias, nullptr, nullptr,
          nullptr, nullptr, nullptr, nullptr);
  };
  auto fattn = [&](bool causal, const bf16* qb, bf16* ao) {
    if (causal) k_fattn<true><<<dim3(16, kBH), 256, 0, stream>>>(qb, qb + 1048576, qb + 2097152, ao);
    else        k_fattn<false><<<dim3(16, kBH), 256, 0, stream>>>(qb, qb + 1048576, qb + 2097152, ao);
  };
  auto out_proj = [&](const bf16* ao, const bf16* wt, const float* bias, float* xio) {
    k_gemm<32, 64, ST_F32, true, false, true, 3, false, false, false>
        <<<dim3(8, 64, 1), 256, 0, stream>>>(
        ao, 512, 0, wt + 3 * 262144, 512, 0, xio, 512, 0, 512, 1.f, bias + 3 * 512,
        xio, nullptr, nullptr, nullptr, nullptr, nullptr);
  };
  auto LN = [&](const float* x, const float* g, const float* b, bf16* out) {
    k_ln<<<kM / 4, 256, 0, stream>>>(x, g, b, out);
  };
  auto ffn = [&](float* xio, const bf16* w1t, const float* b1, const bf16* w2t,
                 const float* b2) {
    k_gemm<64, 64, ST_BF16, true, true, false, 3, false, false, false>
        <<<dim3(32, 32, 1), 256, 0, stream>>>(
        hbuf, 512, 0, w1t, 512, 0, ffn_mid, kF, 0, 512, 1.f, b1, nullptr, nullptr,
        nullptr, nullptr, nullptr, nullptr);
    k_gemm<32, 64, ST_F32, true, false, true, 3, false, false, false>
        <<<dim3(8, 64, 1), 256, 0, stream>>>(
        ffn_mid, 2048, 0, w2t, 2048, 0, xio, 512, 0, 2048, 1.f, b2, xio, nullptr,
        nullptr, nullptr, nullptr, nullptr);
  };

  // ---- PAIRED phase: enc-l0 attn || dec-l0 self-attn
  k_gemm<64, 64, ST_QKV, true, false, false, 3, false, false, true>
      <<<dim3(24, 64, 1), 256, 0, stream>>>(
      hbuf, 512, 0, enc_attn_wt, 512, 0, Qb, 0, 0, 512, 1.f, enc_attn_b, nullptr,
      hbuf2, dec_self_wt, Qb2, dec_self_b, nullptr);
  k_fattn2<<<dim3(16, 2 * kBH), 256, 0, stream>>>(Qb, attn_o, 0, Qb2, attn_o2, 1);
  k_gemm<32, 64, ST_F32, true, false, true, 3, false, false, true>
      <<<dim3(8, 128, 1), 256, 0, stream>>>(
      attn_o, 512, 0, enc_attn_wt + 3 * 262144, 512, 0, x_enc, 512, 0, 512, 1.f,
      enc_attn_b + 3 * 512, x_enc,
      attn_o2, dec_self_wt + 3 * 262144, x_dec, dec_self_b + 3 * 512, x_dec);
  k_ln2<<<dim3(kM / 4, 2), 256, 0, stream>>>(
      x_enc, enc_ln_g + 512, enc_ln_b + 512, hbuf,
      x_dec, dec_ln_g + 512, dec_ln_b + 512, hbuf2);

  // ---- encoder remainder
  ffn(x_enc, enc_f1t, enc_ffn_b1, enc_f2t, enc_ffn_b2);                 // layer 0 FFN
  LN(x_enc, enc_ln_g + 1024, enc_ln_b + 1024, hbuf);                    // l1 LN1
  qkv(hbuf, enc_attn_wt + 1048576, enc_attn_b + 2048, nullptr);
  fattn(false, Qb, attn_o);
  out_proj(attn_o, enc_attn_wt + 1048576, enc_attn_b + 2048, x_enc);
  LN(x_enc, enc_ln_g + 1024 + 512, enc_ln_b + 1024 + 512, hbuf);        // l1 LN2
  ffn(x_enc, enc_f1t + 1048576, enc_ffn_b1 + 2048, enc_f2t + 1048576, enc_ffn_b2 + 512);
  LN(x_enc, enc_norm_g, enc_norm_b, enc_bf);                            // final LN

  // ---- decoder (l0 resumes at cross-attn; hbuf2 holds LN2(x_dec))
  for (int i = 0; i < 2; ++i) {
    const bf16* wts = dec_self_wt + (size_t)i * 1048576;
    const float* bs = dec_self_b + i * 2048;
    const bf16* wtc = dec_cross_wt + (size_t)i * 1048576;
    const float* bc = dec_cross_b + i * 2048;
    if (i == 1) {
      LN(x_dec, dec_ln_g + 1536, dec_ln_b + 1536, hbuf);                // l1 LN1
      qkv(hbuf, wts, bs, nullptr);
      fattn(true, Qb, attn_o);
      out_proj(attn_o, wts, bs, x_dec);
      LN(x_dec, dec_ln_g + 1536 + 512, dec_ln_b + 1536 + 512, hbuf);    // l1 LN2
    }
    const bf16* qsrc = (i == 0) ? hbuf2 : hbuf;
    qkv(qsrc, wtc, bc, enc_bf);                                         // cross QKV
    fattn(false, Qb, attn_o);
    out_proj(attn_o, wtc, bc, x_dec);
    LN(x_dec, dec_ln_g + i * 1536 + 1024, dec_ln_b + i * 1536 + 1024, hbuf);  // LN3
    ffn(x_dec, dec_f1t + (size_t)i * 1048576, dec_ffn_b1 + i * 2048,
        dec_f2t + (size_t)i * 1048576, dec_ffn_b2 + i * 512);
  }
  LN(x_dec, dec_norm_g, dec_norm_b, hbuf);                              // final LN

  // logits -> log_softmax
  k_proj256<<<dim3(125, 8), 512, 0, stream>>>(hbuf, proj_wt, logits, proj_b);
  k_lsm_bf<<<kM, 640, 0, stream>>>(logits, (float*)d_out);
}